// Round 8
// baseline (253.149 us; speedup 1.0000x reference)
//
#include <hip/hip_runtime.h>
#include <hip/hip_bf16.h>

// Problem: CausalSelfAttention  B=2, T=2048, C=1024, H=16, D=64
// Round 20: fix R19's fusion race. R19 failed (absmax 6.75): VT aliases xl,
// and the fused qkv dispatch had V-blocks writing VT(=xl) while QK-blocks
// still read Al(=xl). Fix: runtime ws_size check --
//   ws_size >= 70MB: VT gets a DEDICATED 8MB at offset 62 -> single fused
//     qkv_all (grid 24x32 = 3 blocks/CU, the occupancy experiment, race-free)
//   else: two dispatches via the same kernel (n_off param); same-stream
//     ordering re-legalizes the VT<->xl alias (exact R18 behavior).
// Kernel bodies unchanged from proven versions: QK path = R17 single-buffer
// bf16x3 (66.3us best, 0 conflicts), V path = R13 128^2 V variant,
// attn = R18 raw-barrier + T5 setprio, proj = R18 counted dbuf.
// ws fused (70 MB): Qh 8|Ql 8|Kh 8|Kl 8|xh 8(->Yb)|xl 8|WaTh 6|WaTl 6|WpT 2|VT 8

#define B_  2
#define T_  2048
#define C_  1024
#define H_  16
#define D_  64
#define M_  (B_ * T_)      // 4096
#define N3_ (3 * C_)       // 3072

typedef __attribute__((ext_vector_type(8))) short s16x8;
typedef __attribute__((ext_vector_type(4))) short s16x4;
typedef __attribute__((ext_vector_type(4))) float f32x4;

typedef const __attribute__((address_space(1))) unsigned int gu32_t;
typedef __attribute__((address_space(3))) unsigned int lu32_t;

#define MFMA16(a, b, c) __builtin_amdgcn_mfma_f32_16x16x32_bf16(a, b, c, 0, 0, 0)

__device__ __forceinline__ void gload_lds16(const short* g, short* l) {
    __builtin_amdgcn_global_load_lds((gu32_t*)g, (lu32_t*)l, 16, 0, 0);
}

__device__ __forceinline__ float b2f(unsigned short u) {
    return __uint_as_float(((unsigned)u) << 16);
}
__device__ __forceinline__ unsigned short f2b(float f) {   // RNE bf16 round
    unsigned u = __float_as_uint(f);
    return (unsigned short)((u + 0x7FFFu + ((u >> 16) & 1u)) >> 16);
}
__device__ __forceinline__ float fexp2(float x) {
#if __has_builtin(__builtin_amdgcn_exp2f)
    return __builtin_amdgcn_exp2f(x);
#else
    return exp2f(x);
#endif
}

// ---------------------------------------------------------------------------
// fp32 -> (hi, lo) bf16 split. n multiple of 2048.
// ---------------------------------------------------------------------------
__global__ __launch_bounds__(256) void cvt_split(
    const float* __restrict__ in, short* __restrict__ oh, short* __restrict__ ol, int n)
{
    int i = (blockIdx.x * 256 + threadIdx.x) * 8;
    if (i >= n) return;
    float4 a = *(const float4*)&in[i];
    float4 b = *(const float4*)&in[i + 4];
    float v[8] = {a.x, a.y, a.z, a.w, b.x, b.y, b.z, b.w};
    s16x8 h, l;
    #pragma unroll
    for (int j = 0; j < 8; j++) {
        unsigned short hb = f2b(v[j]);
        h[j] = (short)hb;
        l[j] = (short)f2b(v[j] - b2f(hb));
    }
    *(s16x8*)&oh[i] = h;
    *(s16x8*)&ol[i] = l;
}

// ---------------------------------------------------------------------------
// fp32 [R,Cn] -> (hi,lo) bf16 [Cn,R] transpose+split. grid (Cn/64, R/64).
// ---------------------------------------------------------------------------
__global__ __launch_bounds__(256) void cvtT_split(
    const float* __restrict__ in, short* __restrict__ oh, short* __restrict__ ol,
    int R, int Cn)
{
    __shared__ short th[64][80];
    __shared__ short tl[64][80];
    const int tid = threadIdx.x;
    const int k0 = blockIdx.y * 64;
    const int n0 = blockIdx.x * 64;
    {
        int rl = tid >> 4, cl = (tid & 15) * 4;
        #pragma unroll
        for (int i = 0; i < 4; i++) {
            int kr = rl + i * 16;
            float4 v4 = *(const float4*)&in[(size_t)(k0 + kr) * Cn + n0 + cl];
            float v[4] = {v4.x, v4.y, v4.z, v4.w};
            #pragma unroll
            for (int j = 0; j < 4; j++) {
                unsigned short hb = f2b(v[j]);
                th[cl + j][kr] = (short)hb;
                tl[cl + j][kr] = (short)f2b(v[j] - b2f(hb));
            }
        }
    }
    __syncthreads();
    {
        int ro = tid >> 2, co = (tid & 3) * 16;
        *(s16x8*)&oh[(size_t)(n0 + ro) * R + k0 + co]     = *(s16x8*)&th[ro][co];
        *(s16x8*)&oh[(size_t)(n0 + ro) * R + k0 + co + 8] = *(s16x8*)&th[ro][co + 8];
        *(s16x8*)&ol[(size_t)(n0 + ro) * R + k0 + co]     = *(s16x8*)&tl[ro][co];
        *(s16x8*)&ol[(size_t)(n0 + ro) * R + k0 + co + 8] = *(s16x8*)&tl[ro][co + 8];
    }
}

// ---------------------------------------------------------------------------
// fp32 [R,Cn] -> bf16 [Cn,R] transpose (single, for W_proj).
// ---------------------------------------------------------------------------
__global__ __launch_bounds__(256) void cvtT_bf16(
    const float* __restrict__ in, short* __restrict__ out, int R, int Cn)
{
    __shared__ short t[64][80];
    const int tid = threadIdx.x;
    const int k0 = blockIdx.y * 64;
    const int n0 = blockIdx.x * 64;
    {
        int rl = tid >> 4, cl = (tid & 15) * 4;
        #pragma unroll
        for (int i = 0; i < 4; i++) {
            int kr = rl + i * 16;
            float4 v = *(const float4*)&in[(size_t)(k0 + kr) * Cn + n0 + cl];
            t[cl + 0][kr] = (short)f2b(v.x);
            t[cl + 1][kr] = (short)f2b(v.y);
            t[cl + 2][kr] = (short)f2b(v.z);
            t[cl + 3][kr] = (short)f2b(v.w);
        }
    }
    __syncthreads();
    {
        int ro = tid >> 2, co = (tid & 3) * 16;
        *(s16x8*)&out[(size_t)(n0 + ro) * R + k0 + co]     = *(s16x8*)&t[ro][co];
        *(s16x8*)&out[(size_t)(n0 + ro) * R + k0 + co + 8] = *(s16x8*)&t[ro][co + 8];
    }
}

// ---------------------------------------------------------------------------
// qkv_all: QKV GEMM, logical n0 = blockIdx.x*128 + n_off.
// n0 < 2048 -> Q,K columns: bf16x3, hi/lo scatter, Q pre-scaled 8*log2(e).
// n0 >= 2048 -> V columns: bf16x1, scatter TRANSPOSED -> VT [B,H,D,T].
// Fused launch: grid (24,32), n_off=0 (needs non-aliased VT!).
// Split launch: grid (16,32) n_off=0, then grid (8,32) n_off=2048.
// R17 single-buffer 2-barrier loop, 32 KB LDS, 0-conflict granule swizzle.
// ---------------------------------------------------------------------------
__global__ __launch_bounds__(256) void qkv_all(
    const short* __restrict__ Ah, const short* __restrict__ Al,
    const short* __restrict__ BTh, const short* __restrict__ BTl,
    const float* __restrict__ bias,
    short* __restrict__ Qh, short* __restrict__ Ql,
    short* __restrict__ Kh, short* __restrict__ Kl,
    short* __restrict__ VT, int n_off)
{
    __shared__ short Ash[128 * 32], Asl[128 * 32];
    __shared__ short Bsh[128 * 32], Bsl[128 * 32];   // 32 KB

    const int tid  = threadIdx.x;
    const int wave = tid >> 6, lane = tid & 63;
    const int wm = wave >> 1, wn = wave & 1;
    const int lm = lane & 15, lq = lane >> 4;
    const int m0 = blockIdx.y * 128;
    const int n0 = blockIdx.x * 128 + n_off;
    const int gr  = (lane >> 2);
    // swizzled SOURCE granule: slot (row,g) holds global granule g^((row>>1)&3)
    const int gc  = (((lane & 3) ^ ((lane >> 3) & 3)) << 3);
    // swizzled READ col: logical granule lq of row-in-seg lm lives at lq^((lm>>1)&3)
    const int sg  = ((lq ^ ((lm >> 1) & 3)) << 3);

    f32x4 acc[4][4] = {};

    if (n0 < 2048) {
        // ================= Q,K path: bf16x3 =================
        for (int k0 = 0; k0 < C_; k0 += 32) {
            __syncthreads();
            #pragma unroll
            for (int j = 0; j < 2; j++) {
                int s = wave * 2 + j;
                int row = s * 16 + gr;
                size_t ga = (size_t)(m0 + row) * C_ + k0 + gc;
                size_t gb = (size_t)(n0 + row) * C_ + k0 + gc;
                gload_lds16(&Ah[ga],  &Ash[s * 512]);
                gload_lds16(&Al[ga],  &Asl[s * 512]);
                gload_lds16(&BTh[gb], &Bsh[s * 512]);
                gload_lds16(&BTl[gb], &Bsl[s * 512]);
            }
            __syncthreads();

            s16x8 ah[4], al[4], bh[4], bl[4];
            #pragma unroll
            for (int mi = 0; mi < 4; mi++) {
                int r = wm * 64 + mi * 16 + lm;
                ah[mi] = *(const s16x8*)&Ash[r * 32 + sg];
                al[mi] = *(const s16x8*)&Asl[r * 32 + sg];
            }
            #pragma unroll
            for (int nj = 0; nj < 4; nj++) {
                int r = wn * 64 + nj * 16 + lm;
                bh[nj] = *(const s16x8*)&Bsh[r * 32 + sg];
                bl[nj] = *(const s16x8*)&Bsl[r * 32 + sg];
            }
            #pragma unroll
            for (int mi = 0; mi < 4; mi++)
                #pragma unroll
                for (int nj = 0; nj < 4; nj++) {
                    acc[mi][nj] = MFMA16(ah[mi], bh[nj], acc[mi][nj]);
                    acc[mi][nj] = MFMA16(ah[mi], bl[nj], acc[mi][nj]);
                    acc[mi][nj] = MFMA16(al[mi], bh[nj], acc[mi][nj]);
                }
        }

        #pragma unroll
        for (int nj = 0; nj < 4; nj++) {
            int n = n0 + wn * 64 + nj * 16 + lm;
            float bv = bias[n];
            int isK = n >> 10;
            int c = n & (C_ - 1);
            int h = c >> 6, d = c & (D_ - 1);
            short* dh = isK ? Kh : Qh;
            short* dl = isK ? Kl : Ql;
            // Q carries sqrt(D)=8 and log2(e): softmax runs in exp2 domain
            float scale = isK ? 1.0f : 11.541560327111708f;   // 8*log2(e)
            #pragma unroll
            for (int mi = 0; mi < 4; mi++) {
                #pragma unroll
                for (int r = 0; r < 4; r++) {
                    int m  = m0 + wm * 64 + mi * 16 + lq * 4 + r;
                    int bb = m >> 11, t = m & (T_ - 1);
                    float v = (acc[mi][nj][r] + bv) * scale;
                    size_t idx = (((size_t)bb * H_ + h) * T_ + t) * D_ + d;
                    unsigned short hb = f2b(v);
                    dh[idx] = (short)hb;
                    dl[idx] = (short)f2b(v - b2f(hb));
                }
            }
        }
    } else {
        // ================= V path: bf16x1 =================
        for (int k0 = 0; k0 < C_; k0 += 32) {
            __syncthreads();
            #pragma unroll
            for (int j = 0; j < 2; j++) {
                int s = wave * 2 + j;
                int row = s * 16 + gr;
                gload_lds16(&Ah[(size_t)(m0 + row) * C_ + k0 + gc],  &Ash[s * 512]);
                gload_lds16(&BTh[(size_t)(n0 + row) * C_ + k0 + gc], &Bsh[s * 512]);
            }
            __syncthreads();

            s16x8 af[4], bfr[4];
            #pragma unroll
            for (int mi = 0; mi < 4; mi++)
                af[mi] = *(const s16x8*)&Ash[(wm * 64 + mi * 16 + lm) * 32 + sg];
            #pragma unroll
            for (int nj = 0; nj < 4; nj++)
                bfr[nj] = *(const s16x8*)&Bsh[(wn * 64 + nj * 16 + lm) * 32 + sg];
            #pragma unroll
            for (int mi = 0; mi < 4; mi++)
                #pragma unroll
                for (int nj = 0; nj < 4; nj++)
                    acc[mi][nj] = MFMA16(af[mi], bfr[nj], acc[mi][nj]);
        }

        #pragma unroll
        for (int nj = 0; nj < 4; nj++) {
            int n  = n0 + wn * 64 + nj * 16 + lm;     // 2048..3071
            int nv = n - 2048;                        // V channel [0,1024)
            float bv = bias[n];
            int h = nv >> 6, d = nv & (D_ - 1);
            #pragma unroll
            for (int mi = 0; mi < 4; mi++) {
                #pragma unroll
                for (int r = 0; r < 4; r++) {
                    int m  = m0 + wm * 64 + mi * 16 + lq * 4 + r;
                    int bb = m >> 11, t = m & (T_ - 1);
                    VT[(((size_t)bb * H_ + h) * D_ + d) * T_ + t] =
                        (short)f2b(acc[mi][nj][r] + bv);
                }
            }
        }
    }
}

// ---------------------------------------------------------------------------
// proj: out fp32 [M,C] = Yb(bf16) @ WpT(bf16) + bias. 64x128 tile, grid 512.
// LDS 24 KB dbuf, counted-vmcnt pipeline (R18).
// ---------------------------------------------------------------------------
#define V_STAGE(buf, kk) do {                                           \
    {                                                                   \
        int rowA = wave * 16 + gr;                                      \
        gload_lds16(&Ah[(size_t)(m0 + rowA) * C_ + (kk) + gc],          \
                    &Ash[buf][wave * 512]);                             \
        _Pragma("unroll")                                               \
        for (int j = 0; j < 2; j++) {                                   \
            int s = wave * 2 + j;                                       \
            int rowB = s * 16 + gr;                                     \
            gload_lds16(&BTh[(size_t)(n0 + rowB) * C_ + (kk) + gc],     \
                        &Bsh[buf][s * 512]);                            \
        }                                                               \
    }                                                                   \
} while (0)

__global__ __launch_bounds__(256, 4) void proj_mfma(
    const short* __restrict__ Ah, const short* __restrict__ BTh,
    const float* __restrict__ bias, float* __restrict__ out)
{
    __shared__ short Ash[2][64 * 32];
    __shared__ short Bsh[2][128 * 32];

    const int tid  = threadIdx.x;
    const int wave = tid >> 6, lane = tid & 63;
    const int wm = wave >> 1, wn = wave & 1;
    const int lm = lane & 15, lq = lane >> 4;
    const int m0 = blockIdx.y * 64, n0 = blockIdx.x * 128;
    const int gr  = (lane >> 2);
    const int gc  = (((lane & 3) ^ ((lane >> 3) & 3)) << 3);
    const int sg  = ((lq ^ ((lm >> 1) & 3)) << 3);

    f32x4 acc[2][4] = {};

    V_STAGE(0, 0);
    V_STAGE(1, 32);

    for (int it = 0; it < 32; ++it) {
        const int cur = it & 1;
        if (it == 31) asm volatile("s_waitcnt vmcnt(0)" ::: "memory");
        else          asm volatile("s_waitcnt vmcnt(3)" ::: "memory");
        __builtin_amdgcn_s_barrier();
        __builtin_amdgcn_sched_barrier(0);

        s16x8 af[2], bfr[4];
        #pragma unroll
        for (int mi = 0; mi < 2; mi++)
            af[mi] = *(const s16x8*)&Ash[cur][(wm * 32 + mi * 16 + lm) * 32 + sg];
        #pragma unroll
        for (int nj = 0; nj < 4; nj++)
            bfr[nj] = *(const s16x8*)&Bsh[cur][(wn * 64 + nj * 16 + lm) * 32 + sg];
        #pragma unroll
        for (int mi = 0; mi < 2; mi++)
            #pragma unroll
            for (int nj = 0; nj < 4; nj++)
                acc[mi][nj] = MFMA16(af[mi], bfr[nj], acc[mi][nj]);

        __builtin_amdgcn_sched_barrier(0);
        __builtin_amdgcn_s_barrier();
        if (it < 30) V_STAGE(cur, (it + 2) * 32);
    }

    #pragma unroll
    for (int nj = 0; nj < 4; nj++) {
        int n = n0 + wn * 64 + nj * 16 + lm;
        float bv = bias[n];
        #pragma unroll
        for (int mi = 0; mi < 2; mi++) {
            #pragma unroll
            for (int r = 0; r < 4; r++) {
                int m = m0 + wm * 32 + mi * 16 + lq * 4 + r;
                out[(size_t)m * C_ + n] = acc[mi][nj][r] + bv;
            }
        }
    }
}

// ---------------------------------------------------------------------------
// online softmax (exp2 domain) with defer-max (THR=8). S in/out: S^T frag,
// per-thread 16 values for q-row lm. On exit S holds P = exp2(S - m).
// ---------------------------------------------------------------------------
__device__ __forceinline__ void online_sm(
    f32x4 S[4], float& mrow, float& lrow, f32x4 O[4], int quad)
{
    float v[16];
    #pragma unroll
    for (int t = 0; t < 4; t++)
        #pragma unroll
        for (int r = 0; r < 4; r++) v[t * 4 + r] = S[t][r];
    #pragma unroll
    for (int s = 8; s; s >>= 1)
        #pragma unroll
        for (int i = 0; i < s; i++) v[i] = fmaxf(v[i], v[i + s]);
    float rm = v[0];
    rm = fmaxf(rm, __shfl_xor(rm, 16, 64));
    rm = fmaxf(rm, __shfl_xor(rm, 32, 64));
    // defer-max: only rescale when some row grew by > 8 (=2^8 headroom)
    if (!__all(rm - mrow <= 8.f)) {
        float mnew  = fmaxf(mrow, rm);
        float alpha = fexp2(mrow - mnew);
        mrow = mnew;
        lrow *= alpha;
        float al[4];
        #pragma unroll
        for (int r = 0; r < 4; r++) al[r] = __shfl(alpha, quad * 4 + r, 64);
        #pragma unroll
        for (int t = 0; t < 4; t++)
            #pragma unroll
            for (int r = 0; r < 4; r++) O[t][r] *= al[r];
    }
    float sv[16];
    #pragma unroll
    for (int t = 0; t < 4; t++)
        #pragma unroll
        for (int r = 0; r < 4; r++) {
            float p = fexp2(S[t][r] - mrow);
            S[t][r] = p;
            sv[t * 4 + r] = p;
        }
    #pragma unroll
    for (int s = 8; s; s >>= 1)
        #pragma unroll
        for (int i = 0; i < s; i++) sv[i] += sv[i + s];
    float rs = sv[0];
    rs += __shfl_xor(rs, 16, 64);
    rs += __shfl_xor(rs, 32, 64);
    lrow += rs;
}

// ---------------------------------------------------------------------------
// MFMA flash attention, S^T layout, PAIRED q-tiles per block. Grid 512.
// R18 raw-barrier structure (prefetch flies across compute) + T5 setprio
// around the MFMA clusters. LDS 40KB XOR-swizzled, 2 blocks/CU.
// ---------------------------------------------------------------------------
__global__ __launch_bounds__(256, 2) void attn_mfma(
    const short* __restrict__ Qh, const short* __restrict__ Ql,
    const short* __restrict__ Kh, const short* __restrict__ Kl,
    const short* __restrict__ VT, short* __restrict__ Yb)
{
    __shared__ short Ksh[64][64], Ksl[64][64];   // [key][d], XOR-swizzled
    __shared__ short Vt [64][64];                // [d][key], XOR-swizzled
    __shared__ short Ps [4][2][16][64];          // per-wave P slabs (B=0,A=1)

    const int tid  = threadIdx.x;
    const int wave = tid >> 6, lane = tid & 63;
    const int lm   = lane & 15, quad = lane >> 4;
    const int swz  = (lm & 7) << 3;              // read-side XOR (shorts)

    const int bid = blockIdx.x;                  // 512 blocks
    const int xcd = bid & 7;
    const int r_  = bid >> 3;                    // 0..63 per XCD
    const int bhl = r_ & 3;
    const int u   = r_ >> 2;                     // 0..15
    const int g_  = u >> 3, j_ = u & 7;
    const int j   = g_ ? (15 - j_) : j_;         // CU slot pairs j with 15-j
    const int bh  = xcd * 4 + bhl;
    const int b   = bh >> 4, h = bh & (H_ - 1);
    const int qtA = j, qtB = 31 - j;
    const int q0A = qtA * 64, q0B = qtB * 64;
    const size_t base  = (size_t)bh * T_ * D_;   // Q,K: [b,h,t,d]
    const size_t vbase = (size_t)bh * D_ * T_;   // VT:  [b,h,d,t]

    const int src = tid >> 3;                    // staging row 0..31 (+32)
    const int sch = (tid & 7) * 8;               // linear global col (shorts)
    const int wsw = sch ^ ((src & 7) << 3);      // swizzled LDS write col

    // ---- Q frags direct from global (L2-hit, once per block) ----
    s16x8 bqhA[2], bqlA[2], bqhB[2], bqlB[2];
    #pragma unroll
    for (int kc = 0; kc < 2; kc++) {
        size_t ga = base + (size_t)(q0A + wave * 16 + lm) * D_ + kc * 32 + quad * 8;
        size_t gb = base + (size_t)(q0B + wave * 16 + lm) * D_ + kc * 32 + quad * 8;
        bqhA[kc] = *(const s16x8*)&Qh[ga];
        bqlA[kc] = *(const s16x8*)&Ql[ga];
        bqhB[kc] = *(const s16x8*)&Qh[gb];
        bqlB[kc] = *(const s16x8*)&Ql[gb];
    }

    // ---- prefetch k-tile 0 into registers ----
    s16x8 pkh[2], pkl[2], pvt[2];
    #pragma unroll
    for (int i = 0; i < 2; i++) {
        int row = i * 32 + src;
        size_t gk = base + (size_t)row * D_ + sch;
        pkh[i] = *(const s16x8*)&Kh[gk];
        pkl[i] = *(const s16x8*)&Kl[gk];
        pvt[i] = *(const s16x8*)&VT[vbase + (size_t)row * T_ + sch];
    }

    float mA = -INFINITY, lA = 0.f;
    float mB = -INFINITY, lB = 0.f;
    f32x4 OA[4] = {}, OB[4] = {};

    for (int kt = 0; kt <= qtB; kt++) {
        __builtin_amdgcn_s_barrier();             // WAR: prev readers arrived
        #pragma unroll
        for (int i = 0; i < 2; i++) {             // VGPR -> LDS (swizzled)
            int row = i * 32 + src;
            *(s16x8*)&Ksh[row][wsw] = pkh[i];
            *(s16x8*)&Ksl[row][wsw] = pkl[i];
            *(s16x8*)&Vt [row][wsw] = pvt[i];
        }
        if (kt < qtB) {                           // issue next tile's loads
            #pragma unroll
            for (int i = 0; i < 2; i++) {
                int row = i * 32 + src;
                size_t gk = base + (size_t)((kt + 1) * 64 + row) * D_ + sch;
                pkh[i] = *(const s16x8*)&Kh[gk];
                pkl[i] = *(const s16x8*)&Kl[gk];
                pvt[i] = *(const s16x8*)&VT[vbase + (size_t)row * T_ + (kt + 1) * 64 + sch];
            }
        }
        asm volatile("s_waitcnt lgkmcnt(0)" ::: "memory");  // my ds_writes done
        __builtin_amdgcn_s_barrier();             // RAW: all writes visible
        __builtin_amdgcn_sched_barrier(0);        // keep reads below barrier

        const bool doA = (kt <= qtA);
        const int  qg  = wave * 16 + lm;

        f32x4 SB[4] = {}, SA[4] = {};
        __builtin_amdgcn_s_setprio(1);
        if (doA) {
            // dual: one k-frag read feeds 6 MFMAs (two independent chains)
            #pragma unroll
            for (int t = 0; t < 4; t++)
                #pragma unroll
                for (int kc = 0; kc < 2; kc++) {
                    s16x8 kh8 = *(const s16x8*)&Ksh[t * 16 + lm][(kc * 32 + quad * 8) ^ swz];
                    s16x8 kl8 = *(const s16x8*)&Ksl[t * 16 + lm][(kc * 32 + quad * 8) ^ swz];
                    SB[t] = MFMA16(kh8, bqhB[kc], SB[t]);
                    SB[t] = MFMA16(kl8, bqhB[kc], SB[t]);
                    SB[t] = MFMA16(kh8, bqlB[kc], SB[t]);
                    SA[t] = MFMA16(kh8, bqhA[kc], SA[t]);
                    SA[t] = MFMA16(kl8, bqhA[kc], SA[t]);
                    SA[t] = MFMA16(kh8, bqlA[kc], SA[t]);
                }
        } else {
            #pragma unroll
            for (int t = 0; t < 4; t++)
                #pragma unroll
                for (int kc = 0; kc < 2; kc++) {
                    s16x8 kh8 = *(const s16x8*)&Ksh[t * 16 + lm][(kc * 32 + quad * 8) ^ swz];
                    s16x8 kl8 = *(const s16x8*)&Ksl[t * 16 + lm][(kc * 32 + quad * 8) ^ swz];
                    SB[t] = MFMA16(kh8, bqhB[kc], SB[t]);
                    SB[t] = MFMA16(kl8, bqhB[kc], SB[t]);
                    SB[t] = MFMA16(kh8, bqlB[kc], SB[t]);
                }
        }
        __builtin_amdgcn_s_setprio(0);

        // causal masks (scale pre-folded into Q)
        if (kt == qtB) {
            #pragma unroll
            for (int t = 0; t < 4; t++)
                #pragma unroll
                for (int r = 0; r < 4; r++)
                    if ((t * 16 + quad * 4 + r) > qg) SB[t][r] = -INFINITY;
        }
        if (kt == qtA) {
            #pragma unroll
            for (int t = 0; t < 4; t++)
                #pragma unroll
                for (int r = 0; r < 4; r++)
                    if ((t * 16 + quad * 4 + r) > qg) SA[t][r] = -INFINITY;
        }

        // ---- softmax (dual chains are independent) ----
        online_sm(SB, mB, lB, OB, quad);
        if (doA) online_sm(SA, mA, lA, OA, quad);

        // ---- P^T -> Ps (truncating bf16; P in [0, 256]) ----
        #pragma unroll
        for (int t = 0; t < 4; t++) {
            s16x4 p;
            #pragma unroll
            for (int r = 0; r < 4; r++)
                p[r] = (short)(__float_as_uint(SB[t][r]) >> 16);
            *(s16x4*)&Ps[wave][0][lm][(t * 16 + quad * 4) ^ swz] = p;
        }
        if (doA) {
            #pragma unroll
            for (int t = 0; t < 4; t++) {
                s16x4 p;
                #pragma unroll
                for (int r = 0; r < 4; r++)
                    p[r] = (short)(__float_as_uint(SA[t][r]) >> 16);
                *(s16x4*)&Ps[wave][1][lm][(t * 16 + quad * 4) ^ swz] = p;
            }
        }
        // wave-private slabs: no barrier (lgkmcnt ordering within wave)

        // ---- O += P V: shared Vt frag feeds both tiles ----
        s16x8 apB[2], apA[2];
        #pragma unroll
        for (int kc = 0; kc < 2; kc++)
            apB[kc] = *(const s16x8*)&Ps[wave][0][lm][(kc * 32 + quad * 8) ^ swz];
        __builtin_amdgcn_s_setprio(1);
        if (doA) {
            #pragma unroll
            for (int kc = 0; kc < 2; kc++)
                apA[kc] = *(const s16x8*)&Ps[wave][1][lm][(kc * 32 + quad * 8) ^ swz];
            #pragma unroll
            for (int t = 0; t < 4; t++)
                #pragma unroll
                for (int kc = 0; kc < 2; kc++) {
                    s16x8 bv = *(const s16x8*)&Vt[t * 16 + lm][(kc * 32 + quad * 8) ^ swz];
                    OB[t] = MFMA16(apB[kc], bv, OB[t]);
                    OA[t] = MFMA16(apA[kc], bv, OA[t]);
                }
        } else {
            #pragma unroll
            for (int t = 0; t < 4; t++)
                #pragma unroll
                for (int kc = 0; kc < 2; kc++) {
                    s16x8 bv = *(const s16x8*)&Vt[t * 16 + lm][(kc * 32 + quad * 8) ^ swz];
                    OB[t] = MFMA16(apB[kc], bv, OB[t]);
                }
        }
        __builtin_amdgcn_s_setprio(0);
    }

    // ---- epilogue: O row q = wave*16+quad*4+r, col d = t*16+lm ----
    float liA[4], liB[4];
    #pragma unroll
    for (int r = 0; r < 4; r++) {
        liA[r] = 1.0f / __shfl(lA, quad * 4 + r, 64);
        liB[r] = 1.0f / __shfl(lB, quad * 4 + r, 64);
    }
    #pragma unroll
    for (int t = 0; t < 4; t++)
        #pragma unroll
        for (int r = 0; r < 4; r++) {
            int d  = t * 16 + lm;
            int qa = q0A + wave * 16 + quad * 4 + r;
            int qb = q0B + wave * 16 + quad * 4 + r;
            Yb[((size_t)b * T_ + qa) * C_ + h * D_ + d] =
                (short)f2b(OA[t][r] * liA[r]);
            Yb[((size_t)b * T_ + qb) * C_ + h * D_ + d] =
                (short)f2b(OB[t][r] * liB[r]);
        }
}

// ---------------------------------------------------------------------------
extern "C" void kernel_launch(void* const* d_in, const int* in_sizes, int n_in,
                              void* d_out, int out_size, void* d_ws, size_t ws_size,
                              hipStream_t stream)
{
    const float* x      = (const float*)d_in[0];
    const float* W_attn = (const float*)d_in[1];
    const float* b_attn = (const float*)d_in[2];
    const float* W_proj = (const float*)d_in[3];
    const float* b_proj = (const float*)d_in[4];
    float* out = (float*)d_out;

    char* ws = (char*)d_ws;
    const size_t MB = 1024 * 1024;
    short* Qh   = (short*)(ws);            // 8 MB  [ 0, 8)
    short* Ql   = (short*)(ws +  8 * MB);  // 8 MB  [ 8,16)
    short* Kh   = (short*)(ws + 16 * MB);  // 8 MB  [16,24)
    short* Kl   = (short*)(ws + 24 * MB);  // 8 MB  [24,32)
    short* xh   = (short*)(ws + 32 * MB);  // 8 MB  [32,40)  dead after qkv
    short* xl   = (short*)(ws + 40 * MB);  // 8 MB  [40,48)  dead after qkv
    short* WaTh = (short*)(ws + 48 * MB);  // 6 MB  [48,54)
    short* WaTl = (short*)(ws + 54 * MB);  // 6 MB  [54,60)
    short* WpT  = (short*)(ws + 60 * MB);  // 2 MB  [60,62)
    short* Yb   = (short*)(ws + 32 * MB);  // 8 MB  aliases xh (born at attn)

    // VT placement: fused qkv needs a dedicated buffer (xl is still being
    // read by QK blocks in the same dispatch). Fall back to the serialized
    // two-dispatch path (VT aliases xl legally) if ws is too small.
    const bool fused = ws_size >= 70 * MB;
    short* VT = fused ? (short*)(ws + 62 * MB)   // 8 MB [62,70)
                      : (short*)(ws + 40 * MB);  // aliases xl (serialized)

    cvt_split <<<dim3(M_ * C_ / 2048), 256, 0, stream>>>(x, xh, xl, M_ * C_);
    cvtT_split<<<dim3(N3_ / 64, C_ / 64), 256, 0, stream>>>(W_attn, WaTh, WaTl, C_, N3_);
    cvtT_bf16 <<<dim3(C_ / 64, C_ / 64), 256, 0, stream>>>(W_proj, WpT, C_, C_);

    if (fused) {
        qkv_all<<<dim3(24, 32), 256, 0, stream>>>(xh, xl, WaTh, WaTl, b_attn,
                                                  Qh, Ql, Kh, Kl, VT, 0);
    } else {
        qkv_all<<<dim3(16, 32), 256, 0, stream>>>(xh, xl, WaTh, WaTl, b_attn,
                                                  Qh, Ql, Kh, Kl, VT, 0);
        qkv_all<<<dim3(8, 32), 256, 0, stream>>>(xh, xl, WaTh, WaTl, b_attn,
                                                 Qh, Ql, Kh, Kl, VT, 2048);
    }
    attn_mfma<<<dim3(512), 256, 0, stream>>>(Qh, Ql, Kh, Kl, VT, Yb);
    proj_mfma<<<dim3(8, 64), 256, 0, stream>>>(Yb, WpT, b_proj, out);
}

// Round 9
// 246.272 us; speedup vs baseline: 1.0279x; 1.0279x over previous
//
#include <hip/hip_runtime.h>
#include <hip/hip_bf16.h>

// Problem: CausalSelfAttention  B=2, T=2048, C=1024, H=16, D=64
// Round 21: attn serial-depth attack (intra-pair K-split + combine).
// R20 post-mortem: fused qkv = 102us (kill-rule fired: ragged-tail occupancy
// 15%, L2 thrash). qkv reverted to R17-exact (241.6us best) and frozen.
// attn (~58us) is dependency-latency-bound: avg concurrency ~2 blocks/CU and
// serial depth 33 iters in BOTH paired and quad maps. Fix: split pair
// (j,31-j) into two EQUAL blocks: grp0 = tile 31-j kt[0,17) (17 units);
// grp1 = tile j full (j+1, direct Yb write, no combine) + tile 31-j
// kt[17,32-j) (15-j) = 16 units. 1024 blocks all 16-17 units -> 4/CU,
// serial depth 17. Partials (m,l,O-bf16) of tile 31-j dumped to dead
// WaTh/WaTl space; attn_combine (512 blocks, ~3us) merges max-shifted
// partials -> Yb. Per-iteration body = proven R20 single-chain (swizzle,
// defer-max, raw-barrier prefetch, setprio). bf16 partial-O adds ~0.4% rel
// (headroom 0.031 vs 0.103). cvt/qkv/proj = R17-exact.
// ws (62 MB): Qh 8|Ql 8|Kh 8|Kl 8|xh 8(->Yb)|xl 8(->VT)|WaTh+WaTl 12
// (->PO0 4|PO1 4|ML0 .25|ML1 .25 after qkv)|WpT 2

#define B_  2
#define T_  2048
#define C_  1024
#define H_  16
#define D_  64
#define M_  (B_ * T_)      // 4096
#define N3_ (3 * C_)       // 3072

typedef __attribute__((ext_vector_type(8))) short s16x8;
typedef __attribute__((ext_vector_type(4))) short s16x4;
typedef __attribute__((ext_vector_type(4))) float f32x4;

typedef const __attribute__((address_space(1))) unsigned int gu32_t;
typedef __attribute__((address_space(3))) unsigned int lu32_t;

#define MFMA16(a, b, c) __builtin_amdgcn_mfma_f32_16x16x32_bf16(a, b, c, 0, 0, 0)

__device__ __forceinline__ void gload_lds16(const short* g, short* l) {
    __builtin_amdgcn_global_load_lds((gu32_t*)g, (lu32_t*)l, 16, 0, 0);
}

__device__ __forceinline__ float b2f(unsigned short u) {
    return __uint_as_float(((unsigned)u) << 16);
}
__device__ __forceinline__ unsigned short f2b(float f) {   // RNE bf16 round
    unsigned u = __float_as_uint(f);
    return (unsigned short)((u + 0x7FFFu + ((u >> 16) & 1u)) >> 16);
}
__device__ __forceinline__ float fexp2(float x) {
#if __has_builtin(__builtin_amdgcn_exp2f)
    return __builtin_amdgcn_exp2f(x);
#else
    return exp2f(x);
#endif
}

// ---------------------------------------------------------------------------
// fp32 -> (hi, lo) bf16 split. n multiple of 2048.
// ---------------------------------------------------------------------------
__global__ __launch_bounds__(256) void cvt_split(
    const float* __restrict__ in, short* __restrict__ oh, short* __restrict__ ol, int n)
{
    int i = (blockIdx.x * 256 + threadIdx.x) * 8;
    if (i >= n) return;
    float4 a = *(const float4*)&in[i];
    float4 b = *(const float4*)&in[i + 4];
    float v[8] = {a.x, a.y, a.z, a.w, b.x, b.y, b.z, b.w};
    s16x8 h, l;
    #pragma unroll
    for (int j = 0; j < 8; j++) {
        unsigned short hb = f2b(v[j]);
        h[j] = (short)hb;
        l[j] = (short)f2b(v[j] - b2f(hb));
    }
    *(s16x8*)&oh[i] = h;
    *(s16x8*)&ol[i] = l;
}

// ---------------------------------------------------------------------------
// fp32 [R,Cn] -> (hi,lo) bf16 [Cn,R] transpose+split. grid (Cn/64, R/64).
// ---------------------------------------------------------------------------
__global__ __launch_bounds__(256) void cvtT_split(
    const float* __restrict__ in, short* __restrict__ oh, short* __restrict__ ol,
    int R, int Cn)
{
    __shared__ short th[64][80];
    __shared__ short tl[64][80];
    const int tid = threadIdx.x;
    const int k0 = blockIdx.y * 64;
    const int n0 = blockIdx.x * 64;
    {
        int rl = tid >> 4, cl = (tid & 15) * 4;
        #pragma unroll
        for (int i = 0; i < 4; i++) {
            int kr = rl + i * 16;
            float4 v4 = *(const float4*)&in[(size_t)(k0 + kr) * Cn + n0 + cl];
            float v[4] = {v4.x, v4.y, v4.z, v4.w};
            #pragma unroll
            for (int j = 0; j < 4; j++) {
                unsigned short hb = f2b(v[j]);
                th[cl + j][kr] = (short)hb;
                tl[cl + j][kr] = (short)f2b(v[j] - b2f(hb));
            }
        }
    }
    __syncthreads();
    {
        int ro = tid >> 2, co = (tid & 3) * 16;
        *(s16x8*)&oh[(size_t)(n0 + ro) * R + k0 + co]     = *(s16x8*)&th[ro][co];
        *(s16x8*)&oh[(size_t)(n0 + ro) * R + k0 + co + 8] = *(s16x8*)&th[ro][co + 8];
        *(s16x8*)&ol[(size_t)(n0 + ro) * R + k0 + co]     = *(s16x8*)&tl[ro][co];
        *(s16x8*)&ol[(size_t)(n0 + ro) * R + k0 + co + 8] = *(s16x8*)&tl[ro][co + 8];
    }
}

// ---------------------------------------------------------------------------
// fp32 [R,Cn] -> bf16 [Cn,R] transpose (single, for W_proj).
// ---------------------------------------------------------------------------
__global__ __launch_bounds__(256) void cvtT_bf16(
    const float* __restrict__ in, short* __restrict__ out, int R, int Cn)
{
    __shared__ short t[64][80];
    const int tid = threadIdx.x;
    const int k0 = blockIdx.y * 64;
    const int n0 = blockIdx.x * 64;
    {
        int rl = tid >> 4, cl = (tid & 15) * 4;
        #pragma unroll
        for (int i = 0; i < 4; i++) {
            int kr = rl + i * 16;
            float4 v = *(const float4*)&in[(size_t)(k0 + kr) * Cn + n0 + cl];
            t[cl + 0][kr] = (short)f2b(v.x);
            t[cl + 1][kr] = (short)f2b(v.y);
            t[cl + 2][kr] = (short)f2b(v.z);
            t[cl + 3][kr] = (short)f2b(v.w);
        }
    }
    __syncthreads();
    {
        int ro = tid >> 2, co = (tid & 3) * 16;
        *(s16x8*)&out[(size_t)(n0 + ro) * R + k0 + co]     = *(s16x8*)&t[ro][co];
        *(s16x8*)&out[(size_t)(n0 + ro) * R + k0 + co + 8] = *(s16x8*)&t[ro][co + 8];
    }
}

// ---------------------------------------------------------------------------
// qkv_qk: Q,K columns (N=2048), bf16x3, hi/lo scatter. Q pre-scaled by
// 8*log2(e). 128x128 tile, grid (16,32). LDS 32 KB. 0-conflict granule
// swizzle (R17, best measured 66.3us).
// ---------------------------------------------------------------------------
__global__ __launch_bounds__(256) void qkv_qk(
    const short* __restrict__ Ah, const short* __restrict__ Al,
    const short* __restrict__ BTh, const short* __restrict__ BTl,
    const float* __restrict__ bias,
    short* __restrict__ Qh, short* __restrict__ Ql,
    short* __restrict__ Kh, short* __restrict__ Kl)
{
    __shared__ short Ash[128 * 32], Asl[128 * 32];
    __shared__ short Bsh[128 * 32], Bsl[128 * 32];

    const int tid  = threadIdx.x;
    const int wave = tid >> 6, lane = tid & 63;
    const int wm = wave >> 1, wn = wave & 1;
    const int lm = lane & 15, lq = lane >> 4;
    const int m0 = blockIdx.y * 128, n0 = blockIdx.x * 128;
    const int gr  = (lane >> 2);
    const int gc  = (((lane & 3) ^ ((lane >> 3) & 3)) << 3);
    const int sg  = ((lq ^ ((lm >> 1) & 3)) << 3);

    f32x4 acc[4][4] = {};

    for (int k0 = 0; k0 < C_; k0 += 32) {
        __syncthreads();
        #pragma unroll
        for (int j = 0; j < 2; j++) {
            int s = wave * 2 + j;
            int row = s * 16 + gr;
            size_t ga = (size_t)(m0 + row) * C_ + k0 + gc;
            size_t gb = (size_t)(n0 + row) * C_ + k0 + gc;
            gload_lds16(&Ah[ga],  &Ash[s * 512]);
            gload_lds16(&Al[ga],  &Asl[s * 512]);
            gload_lds16(&BTh[gb], &Bsh[s * 512]);
            gload_lds16(&BTl[gb], &Bsl[s * 512]);
        }
        __syncthreads();

        s16x8 ah[4], al[4], bh[4], bl[4];
        #pragma unroll
        for (int mi = 0; mi < 4; mi++) {
            int r = wm * 64 + mi * 16 + lm;
            ah[mi] = *(const s16x8*)&Ash[r * 32 + sg];
            al[mi] = *(const s16x8*)&Asl[r * 32 + sg];
        }
        #pragma unroll
        for (int nj = 0; nj < 4; nj++) {
            int r = wn * 64 + nj * 16 + lm;
            bh[nj] = *(const s16x8*)&Bsh[r * 32 + sg];
            bl[nj] = *(const s16x8*)&Bsl[r * 32 + sg];
        }
        #pragma unroll
        for (int mi = 0; mi < 4; mi++)
            #pragma unroll
            for (int nj = 0; nj < 4; nj++) {
                acc[mi][nj] = MFMA16(ah[mi], bh[nj], acc[mi][nj]);
                acc[mi][nj] = MFMA16(ah[mi], bl[nj], acc[mi][nj]);
                acc[mi][nj] = MFMA16(al[mi], bh[nj], acc[mi][nj]);
            }
    }

    #pragma unroll
    for (int nj = 0; nj < 4; nj++) {
        int n = n0 + wn * 64 + nj * 16 + lm;
        float bv = bias[n];
        int isK = n >> 10;
        int c = n & (C_ - 1);
        int h = c >> 6, d = c & (D_ - 1);
        short* dh = isK ? Kh : Qh;
        short* dl = isK ? Kl : Ql;
        // Q carries sqrt(D)=8 and log2(e): softmax runs in exp2 domain
        float scale = isK ? 1.0f : 11.541560327111708f;   // 8*log2(e)
        #pragma unroll
        for (int mi = 0; mi < 4; mi++) {
            #pragma unroll
            for (int r = 0; r < 4; r++) {
                int m  = m0 + wm * 64 + mi * 16 + lq * 4 + r;
                int bb = m >> 11, t = m & (T_ - 1);
                float v = (acc[mi][nj][r] + bv) * scale;
                size_t idx = (((size_t)bb * H_ + h) * T_ + t) * D_ + d;
                unsigned short hb = f2b(v);
                dh[idx] = (short)hb;
                dl[idx] = (short)f2b(v - b2f(hb));
            }
        }
    }
}

// ---------------------------------------------------------------------------
// qkv_v: V columns (N=1024), single bf16, scatter TRANSPOSED -> VT [B,H,D,T].
// 64x128 tile, grid (8,64) = 512 blocks. Swizzled LDS. (R17)
// ---------------------------------------------------------------------------
__global__ __launch_bounds__(256, 4) void qkv_v(
    const short* __restrict__ Ah, const short* __restrict__ BTh,
    const float* __restrict__ bias, short* __restrict__ VT)
{
    __shared__ short Ash[64 * 32];    // 4 KB
    __shared__ short Bsh[128 * 32];   // 8 KB

    const int tid  = threadIdx.x;
    const int wave = tid >> 6, lane = tid & 63;
    const int wm = wave >> 1, wn = wave & 1;
    const int lm = lane & 15, lq = lane >> 4;
    const int m0 = blockIdx.y * 64, n0 = blockIdx.x * 128;
    const int gr  = (lane >> 2);
    const int gc  = (((lane & 3) ^ ((lane >> 3) & 3)) << 3);
    const int sg  = ((lq ^ ((lm >> 1) & 3)) << 3);

    f32x4 acc[2][4] = {};

    for (int k0 = 0; k0 < C_; k0 += 32) {
        __syncthreads();
        {
            int rowA = wave * 16 + gr;
            gload_lds16(&Ah[(size_t)(m0 + rowA) * C_ + k0 + gc], &Ash[wave * 512]);
            #pragma unroll
            for (int j = 0; j < 2; j++) {
                int s = wave * 2 + j;
                int rowB = s * 16 + gr;
                gload_lds16(&BTh[(size_t)(n0 + rowB) * C_ + k0 + gc], &Bsh[s * 512]);
            }
        }
        __syncthreads();

        s16x8 af[2], bfr[4];
        #pragma unroll
        for (int mi = 0; mi < 2; mi++)
            af[mi] = *(const s16x8*)&Ash[(wm * 32 + mi * 16 + lm) * 32 + sg];
        #pragma unroll
        for (int nj = 0; nj < 4; nj++)
            bfr[nj] = *(const s16x8*)&Bsh[(wn * 64 + nj * 16 + lm) * 32 + sg];
        #pragma unroll
        for (int mi = 0; mi < 2; mi++)
            #pragma unroll
            for (int nj = 0; nj < 4; nj++)
                acc[mi][nj] = MFMA16(af[mi], bfr[nj], acc[mi][nj]);
    }

    #pragma unroll
    for (int nj = 0; nj < 4; nj++) {
        int n = n0 + wn * 64 + nj * 16 + lm;    // [0, 1024) V channel
        float bv = bias[n];
        int h = n >> 6, d = n & (D_ - 1);
        #pragma unroll
        for (int mi = 0; mi < 2; mi++) {
            #pragma unroll
            for (int r = 0; r < 4; r++) {
                int m  = m0 + wm * 32 + mi * 16 + lq * 4 + r;
                int bb = m >> 11, t = m & (T_ - 1);
                VT[(((size_t)bb * H_ + h) * D_ + d) * T_ + t] =
                    (short)f2b(acc[mi][nj][r] + bv);
            }
        }
    }
}

// ---------------------------------------------------------------------------
// proj: out fp32 [M,C] = Yb(bf16) @ WpT(bf16) + bias. 64x128 tile, grid 512.
// Swizzled LDS. (R17)
// ---------------------------------------------------------------------------
__global__ __launch_bounds__(256, 4) void proj_mfma(
    const short* __restrict__ Ah, const short* __restrict__ BTh,
    const float* __restrict__ bias, float* __restrict__ out)
{
    __shared__ short Ash[64 * 32];
    __shared__ short Bsh[128 * 32];

    const int tid  = threadIdx.x;
    const int wave = tid >> 6, lane = tid & 63;
    const int wm = wave >> 1, wn = wave & 1;
    const int lm = lane & 15, lq = lane >> 4;
    const int m0 = blockIdx.y * 64, n0 = blockIdx.x * 128;
    const int gr  = (lane >> 2);
    const int gc  = (((lane & 3) ^ ((lane >> 3) & 3)) << 3);
    const int sg  = ((lq ^ ((lm >> 1) & 3)) << 3);

    f32x4 acc[2][4] = {};

    for (int k0 = 0; k0 < C_; k0 += 32) {
        __syncthreads();
        {
            int rowA = wave * 16 + gr;
            gload_lds16(&Ah[(size_t)(m0 + rowA) * C_ + k0 + gc], &Ash[wave * 512]);
            #pragma unroll
            for (int j = 0; j < 2; j++) {
                int s = wave * 2 + j;
                int rowB = s * 16 + gr;
                gload_lds16(&BTh[(size_t)(n0 + rowB) * C_ + k0 + gc], &Bsh[s * 512]);
            }
        }
        __syncthreads();

        s16x8 af[2], bfr[4];
        #pragma unroll
        for (int mi = 0; mi < 2; mi++)
            af[mi] = *(const s16x8*)&Ash[(wm * 32 + mi * 16 + lm) * 32 + sg];
        #pragma unroll
        for (int nj = 0; nj < 4; nj++)
            bfr[nj] = *(const s16x8*)&Bsh[(wn * 64 + nj * 16 + lm) * 32 + sg];
        #pragma unroll
        for (int mi = 0; mi < 2; mi++)
            #pragma unroll
            for (int nj = 0; nj < 4; nj++)
                acc[mi][nj] = MFMA16(af[mi], bfr[nj], acc[mi][nj]);
    }

    #pragma unroll
    for (int nj = 0; nj < 4; nj++) {
        int n = n0 + wn * 64 + nj * 16 + lm;
        float bv = bias[n];
        #pragma unroll
        for (int mi = 0; mi < 2; mi++) {
            #pragma unroll
            for (int r = 0; r < 4; r++) {
                int m = m0 + wm * 32 + mi * 16 + lq * 4 + r;
                out[(size_t)m * C_ + n] = acc[mi][nj][r] + bv;
            }
        }
    }
}

// ---------------------------------------------------------------------------
// online softmax (exp2 domain) with defer-max (THR=8). S in/out: S^T frag,
// per-thread 16 values for q-row lm. On exit S holds P = exp2(S - m).
// ---------------------------------------------------------------------------
__device__ __forceinline__ void online_sm(
    f32x4 S[4], float& mrow, float& lrow, f32x4 O[4], int quad)
{
    float v[16];
    #pragma unroll
    for (int t = 0; t < 4; t++)
        #pragma unroll
        for (int r = 0; r < 4; r++) v[t * 4 + r] = S[t][r];
    #pragma unroll
    for (int s = 8; s; s >>= 1)
        #pragma unroll
        for (int i = 0; i < s; i++) v[i] = fmaxf(v[i], v[i + s]);
    float rm = v[0];
    rm = fmaxf(rm, __shfl_xor(rm, 16, 64));
    rm = fmaxf(rm, __shfl_xor(rm, 32, 64));
    // defer-max: only rescale when some row grew by > 8 (=2^8 headroom)
    if (!__all(rm - mrow <= 8.f)) {
        float mnew  = fmaxf(mrow, rm);
        float alpha = fexp2(mrow - mnew);
        mrow = mnew;
        lrow *= alpha;
        float al[4];
        #pragma unroll
        for (int r = 0; r < 4; r++) al[r] = __shfl(alpha, quad * 4 + r, 64);
        #pragma unroll
        for (int t = 0; t < 4; t++)
            #pragma unroll
            for (int r = 0; r < 4; r++) O[t][r] *= al[r];
    }
    float sv[16];
    #pragma unroll
    for (int t = 0; t < 4; t++)
        #pragma unroll
        for (int r = 0; r < 4; r++) {
            float p = fexp2(S[t][r] - mrow);
            S[t][r] = p;
            sv[t * 4 + r] = p;
        }
    #pragma unroll
    for (int s = 8; s; s >>= 1)
        #pragma unroll
        for (int i = 0; i < s; i++) sv[i] += sv[i + s];
    float rs = sv[0];
    rs += __shfl_xor(rs, 16, 64);
    rs += __shfl_xor(rs, 32, 64);
    lrow += rs;
}

// ---------------------------------------------------------------------------
// attn_split: flash attention with intra-pair K-split. Grid 1024, 4/CU.
// Pair (j, 31-j) of one (b,h) -> 2 blocks:
//   grp0: tile 31-j, kt in [0,17)           (17 units; partial -> PO0/ML0)
//   grp1: tile j FULL (kt 0..j, direct Yb) then tile 31-j kt [17,32-j)
//         (16 units total; partial -> PO1/ML1)
// All blocks 16-17 units -> flat balance, serial depth 17 (was 33).
// Single-chain per-iteration body (R20-proven): XOR-swizzled LDS, raw
// barriers + lgkmcnt (async prefetch), setprio, exp2-domain defer-max SM.
// ---------------------------------------------------------------------------
__global__ __launch_bounds__(256, 4) void attn_split(
    const short* __restrict__ Qh, const short* __restrict__ Ql,
    const short* __restrict__ Kh, const short* __restrict__ Kl,
    const short* __restrict__ VT, short* __restrict__ Yb,
    short* __restrict__ PO0, short* __restrict__ PO1,
    float* __restrict__ ML0, float* __restrict__ ML1)
{
    __shared__ short Ksh[64][64], Ksl[64][64];   // [key][d], XOR-swizzled
    __shared__ short Vt [64][64];                // [d][key], XOR-swizzled
    __shared__ short Ps [4][16][64];             // per-wave P slab

    const int tid  = threadIdx.x;
    const int wave = tid >> 6, lane = tid & 63;
    const int lm   = lane & 15, quad = lane >> 4;
    const int swz  = (lm & 7) << 3;              // read-side XOR (shorts)

    const int bid = blockIdx.x;                  // 1024 blocks
    const int xcd = bid & 7;
    const int r_  = bid >> 3;                    // 0..127 per XCD
    const int bhl = r_ & 3;
    const int u   = r_ >> 2;                     // 0..31
    const int grp = u & 1;
    const int j   = u >> 1;                      // 0..15
    const int bh  = xcd * 4 + bhl;
    const int b   = bh >> 4, h = bh & (H_ - 1);
    const int qtA = j, qtB = 31 - j;
    const int q0A = qtA * 64, q0B = qtB * 64;
    const size_t base  = (size_t)bh * T_ * D_;   // Q,K: [b,h,t,d]
    const size_t vbase = (size_t)bh * D_ * T_;   // VT:  [b,h,d,t]
    const int pI = (bh << 4) | j;                // pair index 0..511

    const int src = tid >> 3;                    // staging row 0..31 (+32)
    const int sch = (tid & 7) * 8;               // linear global col (shorts)
    const int wsw = sch ^ ((src & 7) << 3);      // swizzled LDS write col

    const int nsteps = (grp == 0) ? 17 : 16;

    // ---- Q frags for first phase (grp0: tile qtB; grp1: tile qtA) ----
    int q0 = grp ? q0A : q0B;
    s16x8 bqh[2], bql[2];
    #pragma unroll
    for (int kc = 0; kc < 2; kc++) {
        size_t gq = base + (size_t)(q0 + wave * 16 + lm) * D_ + kc * 32 + quad * 8;
        bqh[kc] = *(const s16x8*)&Qh[gq];
        bql[kc] = *(const s16x8*)&Ql[gq];
    }

    // ---- prefetch k-tile 0 (kt(0)=0 for both groups) ----
    s16x8 pkh[2], pkl[2], pvt[2];
    #pragma unroll
    for (int i = 0; i < 2; i++) {
        int row = i * 32 + src;
        size_t gk = base + (size_t)row * D_ + sch;
        pkh[i] = *(const s16x8*)&Kh[gk];
        pkl[i] = *(const s16x8*)&Kl[gk];
        pvt[i] = *(const s16x8*)&VT[vbase + (size_t)row * T_ + sch];
    }

    float mrow = -INFINITY, lrow = 0.f;
    f32x4 O[4] = {};

    for (int step = 0; step < nsteps; ++step) {
        __builtin_amdgcn_s_barrier();             // WAR: prev readers arrived
        #pragma unroll
        for (int i = 0; i < 2; i++) {             // VGPR -> LDS (swizzled)
            int row = i * 32 + src;
            *(s16x8*)&Ksh[row][wsw] = pkh[i];
            *(s16x8*)&Ksl[row][wsw] = pkl[i];
            *(s16x8*)&Vt [row][wsw] = pvt[i];
        }
        if (step + 1 < nsteps) {                  // issue next tile's loads
            int sn  = step + 1;
            int ktn = sn + ((grp && sn > j) ? (16 - j) : 0);
            #pragma unroll
            for (int i = 0; i < 2; i++) {
                int row = i * 32 + src;
                size_t gk = base + (size_t)(ktn * 64 + row) * D_ + sch;
                pkh[i] = *(const s16x8*)&Kh[gk];
                pkl[i] = *(const s16x8*)&Kl[gk];
                pvt[i] = *(const s16x8*)&VT[vbase + (size_t)row * T_ + ktn * 64 + sch];
            }
        }
        asm volatile("s_waitcnt lgkmcnt(0)" ::: "memory");  // my ds_writes done
        __builtin_amdgcn_s_barrier();             // RAW: all writes visible
        __builtin_amdgcn_sched_barrier(0);        // keep reads below barrier

        const int kt    = step + ((grp && step > j) ? (16 - j) : 0);
        const bool isA  = (grp == 1) && (step <= j);
        const int curQt = isA ? qtA : qtB;
        const int qg    = wave * 16 + lm;

        // ---- S^T = K Q^T (bf16x3), single chain ----
        f32x4 S[4] = {};
        __builtin_amdgcn_s_setprio(1);
        #pragma unroll
        for (int t = 0; t < 4; t++)
            #pragma unroll
            for (int kc = 0; kc < 2; kc++) {
                s16x8 kh8 = *(const s16x8*)&Ksh[t * 16 + lm][(kc * 32 + quad * 8) ^ swz];
                s16x8 kl8 = *(const s16x8*)&Ksl[t * 16 + lm][(kc * 32 + quad * 8) ^ swz];
                S[t] = MFMA16(kh8, bqh[kc], S[t]);
                S[t] = MFMA16(kl8, bqh[kc], S[t]);
                S[t] = MFMA16(kh8, bql[kc], S[t]);
            }
        __builtin_amdgcn_s_setprio(0);

        // causal mask at the diagonal tile (scale pre-folded into Q)
        if (kt == curQt) {
            #pragma unroll
            for (int t = 0; t < 4; t++)
                #pragma unroll
                for (int r = 0; r < 4; r++)
                    if ((t * 16 + quad * 4 + r) > qg) S[t][r] = -INFINITY;
        }

        online_sm(S, mrow, lrow, O, quad);

        // ---- P^T -> Ps (truncating bf16) ----
        #pragma unroll
        for (int t = 0; t < 4; t++) {
            s16x4 p;
            #pragma unroll
            for (int r = 0; r < 4; r++)
                p[r] = (short)(__float_as_uint(S[t][r]) >> 16);
            *(s16x4*)&Ps[wave][lm][(t * 16 + quad * 4) ^ swz] = p;
        }
        // wave-private slab: no barrier (lgkmcnt ordering within wave)

        // ---- O += P V ----
        s16x8 ap[2];
        #pragma unroll
        for (int kc = 0; kc < 2; kc++)
            ap[kc] = *(const s16x8*)&Ps[wave][lm][(kc * 32 + quad * 8) ^ swz];
        __builtin_amdgcn_s_setprio(1);
        #pragma unroll
        for (int t = 0; t < 4; t++)
            #pragma unroll
            for (int kc = 0; kc < 2; kc++) {
                s16x8 bv = *(const s16x8*)&Vt[t * 16 + lm][(kc * 32 + quad * 8) ^ swz];
                O[t] = MFMA16(ap[kc], bv, O[t]);
            }
        __builtin_amdgcn_s_setprio(0);

        // ---- grp1: A-tile complete -> direct epilogue, switch to B ----
        if (grp == 1 && step == j) {
            float li[4];
            #pragma unroll
            for (int r = 0; r < 4; r++)
                li[r] = 1.0f / __shfl(lrow, quad * 4 + r, 64);
            #pragma unroll
            for (int t = 0; t < 4; t++)
                #pragma unroll
                for (int r = 0; r < 4; r++) {
                    int q = q0A + wave * 16 + quad * 4 + r;
                    Yb[((size_t)b * T_ + q) * C_ + h * D_ + t * 16 + lm] =
                        (short)f2b(O[t][r] * li[r]);
                }
            mrow = -INFINITY; lrow = 0.f;
            #pragma unroll
            for (int t = 0; t < 4; t++)
                #pragma unroll
                for (int r = 0; r < 4; r++) O[t][r] = 0.f;
            // load B-tile Q frags (reuse registers; A frags dead)
            #pragma unroll
            for (int kc = 0; kc < 2; kc++) {
                size_t gq = base + (size_t)(q0B + wave * 16 + lm) * D_ + kc * 32 + quad * 8;
                bqh[kc] = *(const s16x8*)&Qh[gq];
                bql[kc] = *(const s16x8*)&Ql[gq];
            }
        }
    }

    // ---- dump partial (m, l, O) for tile qtB ----
    short* POd = grp ? PO1 : PO0;
    float* MLd = grp ? ML1 : ML0;
    if (quad == 0) {
        MLd[pI * 128 + (wave * 16 + lm) * 2 + 0] = mrow;
        MLd[pI * 128 + (wave * 16 + lm) * 2 + 1] = lrow;
    }
    #pragma unroll
    for (int t = 0; t < 4; t++)
        #pragma unroll
        for (int r = 0; r < 4; r++) {
            int rr = wave * 16 + quad * 4 + r;
            POd[((size_t)pI * 64 + rr) * 64 + t * 16 + lm] = (short)f2b(O[t][r]);
        }
}

// ---------------------------------------------------------------------------
// attn_combine: merge the two partials of tile 31-j per pair -> Yb.
// Grid 512 (one block per pair). ~12 MB traffic.
// ---------------------------------------------------------------------------
__global__ __launch_bounds__(256) void attn_combine(
    const short* __restrict__ PO0, const short* __restrict__ PO1,
    const float* __restrict__ ML0, const float* __restrict__ ML1,
    short* __restrict__ Yb)
{
    const int p  = blockIdx.x;          // 0..511
    const int bh = p >> 4, j = p & 15;
    const int b  = bh >> 4, h = bh & (H_ - 1);
    const int q0B = (31 - j) * 64;
    const int t  = threadIdx.x;
    const int r  = t >> 2, cs = (t & 3) * 16;

    float m0 = ML0[p * 128 + r * 2 + 0], l0 = ML0[p * 128 + r * 2 + 1];
    float m1 = ML1[p * 128 + r * 2 + 0], l1 = ML1[p * 128 + r * 2 + 1];
    float mC = fmaxf(m0, m1);
    float a0 = fexp2(m0 - mC), a1 = fexp2(m1 - mC);   // exp2(-inf)=0 handles empty
    float li = 1.0f / (a0 * l0 + a1 * l1);

    const short* p0 = &PO0[((size_t)p * 64 + r) * 64 + cs];
    const short* p1 = &PO1[((size_t)p * 64 + r) * 64 + cs];
    short* y = &Yb[((size_t)b * T_ + q0B + r) * C_ + h * D_ + cs];
    #pragma unroll
    for (int s = 0; s < 2; s++) {
        s16x8 o0 = *(const s16x8*)&p0[s * 8];
        s16x8 o1 = *(const s16x8*)&p1[s * 8];
        s16x8 o;
        #pragma unroll
        for (int e = 0; e < 8; e++) {
            float f = (b2f((unsigned short)o0[e]) * a0 +
                       b2f((unsigned short)o1[e]) * a1) * li;
            o[e] = (short)f2b(f);
        }
        *(s16x8*)&y[s * 8] = o;
    }
}

// ---------------------------------------------------------------------------
extern "C" void kernel_launch(void* const* d_in, const int* in_sizes, int n_in,
                              void* d_out, int out_size, void* d_ws, size_t ws_size,
                              hipStream_t stream)
{
    const float* x      = (const float*)d_in[0];
    const float* W_attn = (const float*)d_in[1];
    const float* b_attn = (const float*)d_in[2];
    const float* W_proj = (const float*)d_in[3];
    const float* b_proj = (const float*)d_in[4];
    float* out = (float*)d_out;

    char* ws = (char*)d_ws;
    const size_t MB = 1024 * 1024;
    short* Qh   = (short*)(ws);            // 8 MB  [ 0, 8)
    short* Ql   = (short*)(ws +  8 * MB);  // 8 MB  [ 8,16)
    short* Kh   = (short*)(ws + 16 * MB);  // 8 MB  [16,24)
    short* Kl   = (short*)(ws + 24 * MB);  // 8 MB  [24,32)
    short* xh   = (short*)(ws + 32 * MB);  // 8 MB  [32,40)  dead after qkv_v
    short* xl   = (short*)(ws + 40 * MB);  // 8 MB  [40,48)  dead after qkv_qk
    short* WaTh = (short*)(ws + 48 * MB);  // 6 MB  [48,54)  dead after qkv
    short* WaTl = (short*)(ws + 54 * MB);  // 6 MB  [54,60)  dead after qkv
    short* WpT  = (short*)(ws + 60 * MB);  // 2 MB  [60,62)
    short* VT   = (short*)(ws + 40 * MB);  // 8 MB  aliases xl (born at qkv_v)
    short* Yb   = (short*)(ws + 32 * MB);  // 8 MB  aliases xh (born at attn)
    // attn partials overlay the dead W_attn staging buffers:
    short* PO0  = (short*)(ws + 48 * MB);  // 4 MB  [48,52)
    short* PO1  = (short*)(ws + 52 * MB);  // 4 MB  [52,56)
    float* ML0  = (float*)(ws + 56 * MB);  // 256 KB
    float* ML1  = (float*)(ws + 56 * MB + 512 * 1024);  // 256 KB

    cvt_split <<<dim3(M_ * C_ / 2048), 256, 0, stream>>>(x, xh, xl, M_ * C_);
    cvtT_split<<<dim3(N3_ / 64, C_ / 64), 256, 0, stream>>>(W_attn, WaTh, WaTl, C_, N3_);
    cvtT_bf16 <<<dim3(C_ / 64, C_ / 64), 256, 0, stream>>>(W_proj, WpT, C_, C_);

    qkv_qk <<<dim3(16, 32), 256, 0, stream>>>(xh, xl, WaTh, WaTl, b_attn,
                                              Qh, Ql, Kh, Kl);
    qkv_v  <<<dim3(8, 64), 256, 0, stream>>>(xh, WaTh + (size_t)2048 * C_,
                                             b_attn + 2048, VT);
    attn_split  <<<dim3(1024), 256, 0, stream>>>(Qh, Ql, Kh, Kl, VT, Yb,
                                                 PO0, PO1, ML0, ML1);
    attn_combine<<<dim3(512), 256, 0, stream>>>(PO0, PO1, ML0, ML1, Yb);
    proj_mfma<<<dim3(8, 64), 256, 0, stream>>>(Yb, WpT, b_proj, out);
}

// Round 10
// 242.963 us; speedup vs baseline: 1.0419x; 1.0136x over previous
//
#include <hip/hip_runtime.h>
#include <hip/hip_bf16.h>

// Problem: CausalSelfAttention  B=2, T=2048, C=1024, H=16, D=64
// Round 22: consolidation. R21's attn K-split was net-neutral (246.3 vs
// R17's 241.6 best) -- depth model killed. Revert ALL compute kernels to
// the R17-measured bodies (qkv_qk 128^2 swizzled 66.3us / qkv_v 64x128 /
// attn paired+syncthreads / proj 64x128). New: the three independent cvt
// kernels merged into ONE grid-partitioned dispatch (cvt_all, 3072 blocks:
// [0,2048) x-split | [2048,2816) W_attn T-split | [2816,3072) W_proj T).
// Block-uniform branch, no ordering deps -> zero numerics risk. 7 -> 5
// dispatches; attacks the ~50us of unaccounted inter-dispatch time.
// ws (62 MB): Qh 8|Ql 8|Kh 8|Kl 8|xh 8(->Yb)|xl 8(->VT)|WaTh 6|WaTl 6|WpT 2

#define B_  2
#define T_  2048
#define C_  1024
#define H_  16
#define D_  64
#define M_  (B_ * T_)      // 4096
#define N3_ (3 * C_)       // 3072

typedef __attribute__((ext_vector_type(8))) short s16x8;
typedef __attribute__((ext_vector_type(4))) short s16x4;
typedef __attribute__((ext_vector_type(4))) float f32x4;

typedef const __attribute__((address_space(1))) unsigned int gu32_t;
typedef __attribute__((address_space(3))) unsigned int lu32_t;

#define MFMA16(a, b, c) __builtin_amdgcn_mfma_f32_16x16x32_bf16(a, b, c, 0, 0, 0)

__device__ __forceinline__ void gload_lds16(const short* g, short* l) {
    __builtin_amdgcn_global_load_lds((gu32_t*)g, (lu32_t*)l, 16, 0, 0);
}

__device__ __forceinline__ float b2f(unsigned short u) {
    return __uint_as_float(((unsigned)u) << 16);
}
__device__ __forceinline__ unsigned short f2b(float f) {   // RNE bf16 round
    unsigned u = __float_as_uint(f);
    return (unsigned short)((u + 0x7FFFu + ((u >> 16) & 1u)) >> 16);
}
__device__ __forceinline__ float fexp2(float x) {
#if __has_builtin(__builtin_amdgcn_exp2f)
    return __builtin_amdgcn_exp2f(x);
#else
    return exp2f(x);
#endif
}

// ---------------------------------------------------------------------------
// cvt_all: one dispatch for all input conversions (grid 3072).
//   bid [0,2048):    x fp32 -> (xh, xl) bf16 hi/lo split
//   bid [2048,2816): W_attn [C,3C] -> (WaTh, WaTl) bf16 [3C,C] T-split
//   bid [2816,3072): W_proj [C,C]  -> WpT bf16 [C,C] transpose
// Branch is uniform per block; regions independent.
// ---------------------------------------------------------------------------
__global__ __launch_bounds__(256) void cvt_all(
    const float* __restrict__ x,  short* __restrict__ xh,   short* __restrict__ xl,
    const float* __restrict__ Wa, short* __restrict__ WaTh, short* __restrict__ WaTl,
    const float* __restrict__ Wp, short* __restrict__ WpT)
{
    __shared__ short th[64][80];
    __shared__ short tl[64][80];
    const int tid = threadIdx.x;
    const int bid = blockIdx.x;

    if (bid < 2048) {
        // ---- x hi/lo split (16 MB fp32 -> 2x 8 MB bf16) ----
        int i = (bid * 256 + tid) * 8;
        float4 a = *(const float4*)&x[i];
        float4 b = *(const float4*)&x[i + 4];
        float v[8] = {a.x, a.y, a.z, a.w, b.x, b.y, b.z, b.w};
        s16x8 h, l;
        #pragma unroll
        for (int j = 0; j < 8; j++) {
            unsigned short hb = f2b(v[j]);
            h[j] = (short)hb;
            l[j] = (short)f2b(v[j] - b2f(hb));
        }
        *(s16x8*)&xh[i] = h;
        *(s16x8*)&xl[i] = l;
        return;
    }

    if (bid < 2816) {
        // ---- W_attn transpose + hi/lo split ----
        int r  = bid - 2048;            // 0..767
        int bx = r % 48, by = r / 48;   // (N3_/64, C_/64)
        const int k0 = by * 64, n0 = bx * 64;
        const int R = C_, Cn = N3_;
        {
            int rl = tid >> 4, cl = (tid & 15) * 4;
            #pragma unroll
            for (int i = 0; i < 4; i++) {
                int kr = rl + i * 16;
                float4 v4 = *(const float4*)&Wa[(size_t)(k0 + kr) * Cn + n0 + cl];
                float v[4] = {v4.x, v4.y, v4.z, v4.w};
                #pragma unroll
                for (int j = 0; j < 4; j++) {
                    unsigned short hb = f2b(v[j]);
                    th[cl + j][kr] = (short)hb;
                    tl[cl + j][kr] = (short)f2b(v[j] - b2f(hb));
                }
            }
        }
        __syncthreads();
        {
            int ro = tid >> 2, co = (tid & 3) * 16;
            *(s16x8*)&WaTh[(size_t)(n0 + ro) * R + k0 + co]     = *(s16x8*)&th[ro][co];
            *(s16x8*)&WaTh[(size_t)(n0 + ro) * R + k0 + co + 8] = *(s16x8*)&th[ro][co + 8];
            *(s16x8*)&WaTl[(size_t)(n0 + ro) * R + k0 + co]     = *(s16x8*)&tl[ro][co];
            *(s16x8*)&WaTl[(size_t)(n0 + ro) * R + k0 + co + 8] = *(s16x8*)&tl[ro][co + 8];
        }
        return;
    }

    {
        // ---- W_proj transpose (single bf16) ----
        int r  = bid - 2816;            // 0..255
        int bx = r & 15, by = r >> 4;   // (C_/64, C_/64)
        const int k0 = by * 64, n0 = bx * 64;
        const int R = C_, Cn = C_;
        {
            int rl = tid >> 4, cl = (tid & 15) * 4;
            #pragma unroll
            for (int i = 0; i < 4; i++) {
                int kr = rl + i * 16;
                float4 v = *(const float4*)&Wp[(size_t)(k0 + kr) * Cn + n0 + cl];
                th[cl + 0][kr] = (short)f2b(v.x);
                th[cl + 1][kr] = (short)f2b(v.y);
                th[cl + 2][kr] = (short)f2b(v.z);
                th[cl + 3][kr] = (short)f2b(v.w);
            }
        }
        __syncthreads();
        {
            int ro = tid >> 2, co = (tid & 3) * 16;
            *(s16x8*)&WpT[(size_t)(n0 + ro) * R + k0 + co]     = *(s16x8*)&th[ro][co];
            *(s16x8*)&WpT[(size_t)(n0 + ro) * R + k0 + co + 8] = *(s16x8*)&th[ro][co + 8];
        }
    }
}

// ---------------------------------------------------------------------------
// qkv_qk: Q,K columns (N=2048), bf16x3, hi/lo scatter. Q pre-scaled by
// 8*log2(e). 128x128 tile, grid (16,32). LDS 32 KB. 0-conflict granule
// swizzle (R17, best measured 66.3us).
// ---------------------------------------------------------------------------
__global__ __launch_bounds__(256) void qkv_qk(
    const short* __restrict__ Ah, const short* __restrict__ Al,
    const short* __restrict__ BTh, const short* __restrict__ BTl,
    const float* __restrict__ bias,
    short* __restrict__ Qh, short* __restrict__ Ql,
    short* __restrict__ Kh, short* __restrict__ Kl)
{
    __shared__ short Ash[128 * 32], Asl[128 * 32];
    __shared__ short Bsh[128 * 32], Bsl[128 * 32];

    const int tid  = threadIdx.x;
    const int wave = tid >> 6, lane = tid & 63;
    const int wm = wave >> 1, wn = wave & 1;
    const int lm = lane & 15, lq = lane >> 4;
    const int m0 = blockIdx.y * 128, n0 = blockIdx.x * 128;
    const int gr  = (lane >> 2);
    // swizzled SOURCE granule: slot (row,g) holds global granule g^((row>>1)&3)
    const int gc  = (((lane & 3) ^ ((lane >> 3) & 3)) << 3);
    // swizzled READ col: logical granule lq of row-in-seg lm lives at lq^((lm>>1)&3)
    const int sg  = ((lq ^ ((lm >> 1) & 3)) << 3);

    f32x4 acc[4][4] = {};

    for (int k0 = 0; k0 < C_; k0 += 32) {
        __syncthreads();
        #pragma unroll
        for (int j = 0; j < 2; j++) {
            int s = wave * 2 + j;
            int row = s * 16 + gr;
            size_t ga = (size_t)(m0 + row) * C_ + k0 + gc;
            size_t gb = (size_t)(n0 + row) * C_ + k0 + gc;
            gload_lds16(&Ah[ga],  &Ash[s * 512]);
            gload_lds16(&Al[ga],  &Asl[s * 512]);
            gload_lds16(&BTh[gb], &Bsh[s * 512]);
            gload_lds16(&BTl[gb], &Bsl[s * 512]);
        }
        __syncthreads();

        s16x8 ah[4], al[4], bh[4], bl[4];
        #pragma unroll
        for (int mi = 0; mi < 4; mi++) {
            int r = wm * 64 + mi * 16 + lm;
            ah[mi] = *(const s16x8*)&Ash[r * 32 + sg];
            al[mi] = *(const s16x8*)&Asl[r * 32 + sg];
        }
        #pragma unroll
        for (int nj = 0; nj < 4; nj++) {
            int r = wn * 64 + nj * 16 + lm;
            bh[nj] = *(const s16x8*)&Bsh[r * 32 + sg];
            bl[nj] = *(const s16x8*)&Bsl[r * 32 + sg];
        }
        #pragma unroll
        for (int mi = 0; mi < 4; mi++)
            #pragma unroll
            for (int nj = 0; nj < 4; nj++) {
                acc[mi][nj] = MFMA16(ah[mi], bh[nj], acc[mi][nj]);
                acc[mi][nj] = MFMA16(ah[mi], bl[nj], acc[mi][nj]);
                acc[mi][nj] = MFMA16(al[mi], bh[nj], acc[mi][nj]);
            }
    }

    #pragma unroll
    for (int nj = 0; nj < 4; nj++) {
        int n = n0 + wn * 64 + nj * 16 + lm;
        float bv = bias[n];
        int isK = n >> 10;
        int c = n & (C_ - 1);
        int h = c >> 6, d = c & (D_ - 1);
        short* dh = isK ? Kh : Qh;
        short* dl = isK ? Kl : Ql;
        // Q carries sqrt(D)=8 and log2(e): softmax runs in exp2 domain
        float scale = isK ? 1.0f : 11.541560327111708f;   // 8*log2(e)
        #pragma unroll
        for (int mi = 0; mi < 4; mi++) {
            #pragma unroll
            for (int r = 0; r < 4; r++) {
                int m  = m0 + wm * 64 + mi * 16 + lq * 4 + r;
                int bb = m >> 11, t = m & (T_ - 1);
                float v = (acc[mi][nj][r] + bv) * scale;
                size_t idx = (((size_t)bb * H_ + h) * T_ + t) * D_ + d;
                unsigned short hb = f2b(v);
                dh[idx] = (short)hb;
                dl[idx] = (short)f2b(v - b2f(hb));
            }
        }
    }
}

// ---------------------------------------------------------------------------
// qkv_v: V columns (N=1024), single bf16, scatter TRANSPOSED -> VT [B,H,D,T].
// 64x128 tile, grid (8,64) = 512 blocks. Swizzled LDS. (R17)
// ---------------------------------------------------------------------------
__global__ __launch_bounds__(256, 4) void qkv_v(
    const short* __restrict__ Ah, const short* __restrict__ BTh,
    const float* __restrict__ bias, short* __restrict__ VT)
{
    __shared__ short Ash[64 * 32];    // 4 KB
    __shared__ short Bsh[128 * 32];   // 8 KB

    const int tid  = threadIdx.x;
    const int wave = tid >> 6, lane = tid & 63;
    const int wm = wave >> 1, wn = wave & 1;
    const int lm = lane & 15, lq = lane >> 4;
    const int m0 = blockIdx.y * 64, n0 = blockIdx.x * 128;
    const int gr  = (lane >> 2);
    const int gc  = (((lane & 3) ^ ((lane >> 3) & 3)) << 3);
    const int sg  = ((lq ^ ((lm >> 1) & 3)) << 3);

    f32x4 acc[2][4] = {};

    for (int k0 = 0; k0 < C_; k0 += 32) {
        __syncthreads();
        {
            int rowA = wave * 16 + gr;
            gload_lds16(&Ah[(size_t)(m0 + rowA) * C_ + k0 + gc], &Ash[wave * 512]);
            #pragma unroll
            for (int j = 0; j < 2; j++) {
                int s = wave * 2 + j;
                int rowB = s * 16 + gr;
                gload_lds16(&BTh[(size_t)(n0 + rowB) * C_ + k0 + gc], &Bsh[s * 512]);
            }
        }
        __syncthreads();

        s16x8 af[2], bfr[4];
        #pragma unroll
        for (int mi = 0; mi < 2; mi++)
            af[mi] = *(const s16x8*)&Ash[(wm * 32 + mi * 16 + lm) * 32 + sg];
        #pragma unroll
        for (int nj = 0; nj < 4; nj++)
            bfr[nj] = *(const s16x8*)&Bsh[(wn * 64 + nj * 16 + lm) * 32 + sg];
        #pragma unroll
        for (int mi = 0; mi < 2; mi++)
            #pragma unroll
            for (int nj = 0; nj < 4; nj++)
                acc[mi][nj] = MFMA16(af[mi], bfr[nj], acc[mi][nj]);
    }

    #pragma unroll
    for (int nj = 0; nj < 4; nj++) {
        int n = n0 + wn * 64 + nj * 16 + lm;    // [0, 1024) V channel
        float bv = bias[n];
        int h = n >> 6, d = n & (D_ - 1);
        #pragma unroll
        for (int mi = 0; mi < 2; mi++) {
            #pragma unroll
            for (int r = 0; r < 4; r++) {
                int m  = m0 + wm * 32 + mi * 16 + lq * 4 + r;
                int bb = m >> 11, t = m & (T_ - 1);
                VT[(((size_t)bb * H_ + h) * D_ + d) * T_ + t] =
                    (short)f2b(acc[mi][nj][r] + bv);
            }
        }
    }
}

// ---------------------------------------------------------------------------
// proj: out fp32 [M,C] = Yb(bf16) @ WpT(bf16) + bias. 64x128 tile, grid 512.
// Swizzled LDS. (R17)
// ---------------------------------------------------------------------------
__global__ __launch_bounds__(256, 4) void proj_mfma(
    const short* __restrict__ Ah, const short* __restrict__ BTh,
    const float* __restrict__ bias, float* __restrict__ out)
{
    __shared__ short Ash[64 * 32];
    __shared__ short Bsh[128 * 32];

    const int tid  = threadIdx.x;
    const int wave = tid >> 6, lane = tid & 63;
    const int wm = wave >> 1, wn = wave & 1;
    const int lm = lane & 15, lq = lane >> 4;
    const int m0 = blockIdx.y * 64, n0 = blockIdx.x * 128;
    const int gr  = (lane >> 2);
    const int gc  = (((lane & 3) ^ ((lane >> 3) & 3)) << 3);
    const int sg  = ((lq ^ ((lm >> 1) & 3)) << 3);

    f32x4 acc[2][4] = {};

    for (int k0 = 0; k0 < C_; k0 += 32) {
        __syncthreads();
        {
            int rowA = wave * 16 + gr;
            gload_lds16(&Ah[(size_t)(m0 + rowA) * C_ + k0 + gc], &Ash[wave * 512]);
            #pragma unroll
            for (int j = 0; j < 2; j++) {
                int s = wave * 2 + j;
                int rowB = s * 16 + gr;
                gload_lds16(&BTh[(size_t)(n0 + rowB) * C_ + k0 + gc], &Bsh[s * 512]);
            }
        }
        __syncthreads();

        s16x8 af[2], bfr[4];
        #pragma unroll
        for (int mi = 0; mi < 2; mi++)
            af[mi] = *(const s16x8*)&Ash[(wm * 32 + mi * 16 + lm) * 32 + sg];
        #pragma unroll
        for (int nj = 0; nj < 4; nj++)
            bfr[nj] = *(const s16x8*)&Bsh[(wn * 64 + nj * 16 + lm) * 32 + sg];
        #pragma unroll
        for (int mi = 0; mi < 2; mi++)
            #pragma unroll
            for (int nj = 0; nj < 4; nj++)
                acc[mi][nj] = MFMA16(af[mi], bfr[nj], acc[mi][nj]);
    }

    #pragma unroll
    for (int nj = 0; nj < 4; nj++) {
        int n = n0 + wn * 64 + nj * 16 + lm;
        float bv = bias[n];
        #pragma unroll
        for (int mi = 0; mi < 2; mi++) {
            #pragma unroll
            for (int r = 0; r < 4; r++) {
                int m = m0 + wm * 32 + mi * 16 + lq * 4 + r;
                out[(size_t)m * C_ + n] = acc[mi][nj][r] + bv;
            }
        }
    }
}

// ---------------------------------------------------------------------------
// online softmax (exp2 domain) with defer-max (THR=8). S in/out: S^T frag,
// per-thread 16 values for q-row lm. On exit S holds P = exp2(S - m).
// ---------------------------------------------------------------------------
__device__ __forceinline__ void online_sm(
    f32x4 S[4], float& mrow, float& lrow, f32x4 O[4], int quad)
{
    float v[16];
    #pragma unroll
    for (int t = 0; t < 4; t++)
        #pragma unroll
        for (int r = 0; r < 4; r++) v[t * 4 + r] = S[t][r];
    #pragma unroll
    for (int s = 8; s; s >>= 1)
        #pragma unroll
        for (int i = 0; i < s; i++) v[i] = fmaxf(v[i], v[i + s]);
    float rm = v[0];
    rm = fmaxf(rm, __shfl_xor(rm, 16, 64));
    rm = fmaxf(rm, __shfl_xor(rm, 32, 64));
    // defer-max: only rescale when some row grew by > 8 (=2^8 headroom)
    if (!__all(rm - mrow <= 8.f)) {
        float mnew  = fmaxf(mrow, rm);
        float alpha = fexp2(mrow - mnew);
        mrow = mnew;
        lrow *= alpha;
        float al[4];
        #pragma unroll
        for (int r = 0; r < 4; r++) al[r] = __shfl(alpha, quad * 4 + r, 64);
        #pragma unroll
        for (int t = 0; t < 4; t++)
            #pragma unroll
            for (int r = 0; r < 4; r++) O[t][r] *= al[r];
    }
    float sv[16];
    #pragma unroll
    for (int t = 0; t < 4; t++)
        #pragma unroll
        for (int r = 0; r < 4; r++) {
            float p = fexp2(S[t][r] - mrow);
            S[t][r] = p;
            sv[t * 4 + r] = p;
        }
    #pragma unroll
    for (int s = 8; s; s >>= 1)
        #pragma unroll
        for (int i = 0; i < s; i++) sv[i] += sv[i + s];
    float rs = sv[0];
    rs += __shfl_xor(rs, 16, 64);
    rs += __shfl_xor(rs, 32, 64);
    lrow += rs;
}

// ---------------------------------------------------------------------------
// MFMA flash attention, S^T layout, PAIRED q-tiles per block. Grid 512.
// Block handles qtA=j (j in 0..15) and qtB=31-j of one (b,h): exactly 33
// compute-units each. K/V staged once per kt, shared by both tiles; for
// kt<=j one LDS k-frag read feeds 6 MFMAs (dual chains = intra-wave ILP).
// Slot map pairs j with 15-j -> per-CU iteration count 49 (constant).
// LDS 40KB, XOR-swizzled [64][64] (conflict-free), 2 blocks/CU.
// Q pre-scaled by 8*log2e; softmax exp2-domain with defer-max. (R17-exact)
// ---------------------------------------------------------------------------
__global__ __launch_bounds__(256, 2) void attn_mfma(
    const short* __restrict__ Qh, const short* __restrict__ Ql,
    const short* __restrict__ Kh, const short* __restrict__ Kl,
    const short* __restrict__ VT, short* __restrict__ Yb)
{
    __shared__ short Ksh[64][64], Ksl[64][64];   // [key][d], XOR-swizzled
    __shared__ short Vt [64][64];                // [d][key], XOR-swizzled
    __shared__ short Ps [4][2][16][64];          // per-wave P slabs (B=0,A=1)

    const int tid  = threadIdx.x;
    const int wave = tid >> 6, lane = tid & 63;
    const int lm   = lane & 15, quad = lane >> 4;
    const int swz  = (lm & 7) << 3;              // read-side XOR (shorts)

    const int bid = blockIdx.x;                  // 512 blocks
    const int xcd = bid & 7;
    const int r_  = bid >> 3;                    // 0..63 per XCD
    const int bhl = r_ & 3;
    const int u   = r_ >> 2;                     // 0..15
    const int g_  = u >> 3, j_ = u & 7;
    const int j   = g_ ? (15 - j_) : j_;         // CU slot pairs j with 15-j
    const int bh  = xcd * 4 + bhl;
    const int b   = bh >> 4, h = bh & (H_ - 1);
    const int qtA = j, qtB = 31 - j;
    const int q0A = qtA * 64, q0B = qtB * 64;
    const size_t base  = (size_t)bh * T_ * D_;   // Q,K: [b,h,t,d]
    const size_t vbase = (size_t)bh * D_ * T_;   // VT:  [b,h,d,t]

    const int src = tid >> 3;                    // staging row 0..31 (+32)
    const int sch = (tid & 7) * 8;               // linear global col (shorts)
    const int wsw = sch ^ ((src & 7) << 3);      // swizzled LDS write col

    // ---- Q frags direct from global (L2-hit, once per block) ----
    s16x8 bqhA[2], bqlA[2], bqhB[2], bqlB[2];
    #pragma unroll
    for (int kc = 0; kc < 2; kc++) {
        size_t ga = base + (size_t)(q0A + wave * 16 + lm) * D_ + kc * 32 + quad * 8;
        size_t gb = base + (size_t)(q0B + wave * 16 + lm) * D_ + kc * 32 + quad * 8;
        bqhA[kc] = *(const s16x8*)&Qh[ga];
        bqlA[kc] = *(const s16x8*)&Ql[ga];
        bqhB[kc] = *(const s16x8*)&Qh[gb];
        bqlB[kc] = *(const s16x8*)&Ql[gb];
    }

    // ---- prefetch k-tile 0 into registers ----
    s16x8 pkh[2], pkl[2], pvt[2];
    #pragma unroll
    for (int i = 0; i < 2; i++) {
        int row = i * 32 + src;
        size_t gk = base + (size_t)row * D_ + sch;
        pkh[i] = *(const s16x8*)&Kh[gk];
        pkl[i] = *(const s16x8*)&Kl[gk];
        pvt[i] = *(const s16x8*)&VT[vbase + (size_t)row * T_ + sch];
    }

    float mA = -INFINITY, lA = 0.f;
    float mB = -INFINITY, lB = 0.f;
    f32x4 OA[4] = {}, OB[4] = {};

    for (int kt = 0; kt <= qtB; kt++) {
        __syncthreads();                          // prev tile's readers done
        #pragma unroll
        for (int i = 0; i < 2; i++) {             // VGPR -> LDS (swizzled)
            int row = i * 32 + src;
            *(s16x8*)&Ksh[row][wsw] = pkh[i];
            *(s16x8*)&Ksl[row][wsw] = pkl[i];
            *(s16x8*)&Vt [row][wsw] = pvt[i];
        }
        if (kt < qtB) {                           // issue next tile's loads
            #pragma unroll
            for (int i = 0; i < 2; i++) {
                int row = i * 32 + src;
                size_t gk = base + (size_t)((kt + 1) * 64 + row) * D_ + sch;
                pkh[i] = *(const s16x8*)&Kh[gk];
                pkl[i] = *(const s16x8*)&Kl[gk];
                pvt[i] = *(const s16x8*)&VT[vbase + (size_t)row * T_ + (kt + 1) * 64 + sch];
            }
        }
        __syncthreads();

        const bool doA = (kt <= qtA);
        const int  qg  = wave * 16 + lm;

        f32x4 SB[4] = {}, SA[4] = {};
        if (doA) {
            // dual: one k-frag read feeds 6 MFMAs (two independent chains)
            #pragma unroll
            for (int t = 0; t < 4; t++)
                #pragma unroll
                for (int kc = 0; kc < 2; kc++) {
                    s16x8 kh8 = *(const s16x8*)&Ksh[t * 16 + lm][(kc * 32 + quad * 8) ^ swz];
                    s16x8 kl8 = *(const s16x8*)&Ksl[t * 16 + lm][(kc * 32 + quad * 8) ^ swz];
                    SB[t] = MFMA16(kh8, bqhB[kc], SB[t]);
                    SB[t] = MFMA16(kl8, bqhB[kc], SB[t]);
                    SB[t] = MFMA16(kh8, bqlB[kc], SB[t]);
                    SA[t] = MFMA16(kh8, bqhA[kc], SA[t]);
                    SA[t] = MFMA16(kl8, bqhA[kc], SA[t]);
                    SA[t] = MFMA16(kh8, bqlA[kc], SA[t]);
                }
        } else {
            #pragma unroll
            for (int t = 0; t < 4; t++)
                #pragma unroll
                for (int kc = 0; kc < 2; kc++) {
                    s16x8 kh8 = *(const s16x8*)&Ksh[t * 16 + lm][(kc * 32 + quad * 8) ^ swz];
                    s16x8 kl8 = *(const s16x8*)&Ksl[t * 16 + lm][(kc * 32 + quad * 8) ^ swz];
                    SB[t] = MFMA16(kh8, bqhB[kc], SB[t]);
                    SB[t] = MFMA16(kl8, bqhB[kc], SB[t]);
                    SB[t] = MFMA16(kh8, bqlB[kc], SB[t]);
                }
        }

        // causal masks (scale pre-folded into Q)
        if (kt == qtB) {
            #pragma unroll
            for (int t = 0; t < 4; t++)
                #pragma unroll
                for (int r = 0; r < 4; r++)
                    if ((t * 16 + quad * 4 + r) > qg) SB[t][r] = -INFINITY;
        }
        if (kt == qtA) {
            #pragma unroll
            for (int t = 0; t < 4; t++)
                #pragma unroll
                for (int r = 0; r < 4; r++)
                    if ((t * 16 + quad * 4 + r) > qg) SA[t][r] = -INFINITY;
        }

        // ---- softmax (dual chains are independent) ----
        online_sm(SB, mB, lB, OB, quad);
        if (doA) online_sm(SA, mA, lA, OA, quad);

        // ---- P^T -> Ps (truncating bf16; P in [0, 256]) ----
        #pragma unroll
        for (int t = 0; t < 4; t++) {
            s16x4 p;
            #pragma unroll
            for (int r = 0; r < 4; r++)
                p[r] = (short)(__float_as_uint(SB[t][r]) >> 16);
            *(s16x4*)&Ps[wave][0][lm][(t * 16 + quad * 4) ^ swz] = p;
        }
        if (doA) {
            #pragma unroll
            for (int t = 0; t < 4; t++) {
                s16x4 p;
                #pragma unroll
                for (int r = 0; r < 4; r++)
                    p[r] = (short)(__float_as_uint(SA[t][r]) >> 16);
                *(s16x4*)&Ps[wave][1][lm][(t * 16 + quad * 4) ^ swz] = p;
            }
        }
        // wave-private slabs: no barrier (lgkmcnt ordering within wave)

        // ---- O += P V: shared Vt frag feeds both tiles ----
        s16x8 apB[2], apA[2];
        #pragma unroll
        for (int kc = 0; kc < 2; kc++)
            apB[kc] = *(const s16x8*)&Ps[wave][0][lm][(kc * 32 + quad * 8) ^ swz];
        if (doA) {
            #pragma unroll
            for (int kc = 0; kc < 2; kc++)
                apA[kc] = *(const s16x8*)&Ps[wave][1][lm][(kc * 32 + quad * 8) ^ swz];
            #pragma unroll
            for (int t = 0; t < 4; t++)
                #pragma unroll
                for (int kc = 0; kc < 2; kc++) {
                    s16x8 bv = *(const s16x8*)&Vt[t * 16 + lm][(kc * 32 + quad * 8) ^ swz];
                    OB[t] = MFMA16(apB[kc], bv, OB[t]);
                    OA[t] = MFMA16(apA[kc], bv, OA[t]);
                }
        } else {
            #pragma unroll
            for (int t = 0; t < 4; t++)
                #pragma unroll
                for (int kc = 0; kc < 2; kc++) {
                    s16x8 bv = *(const s16x8*)&Vt[t * 16 + lm][(kc * 32 + quad * 8) ^ swz];
                    OB[t] = MFMA16(apB[kc], bv, OB[t]);
                }
        }
    }

    // ---- epilogue: O row q = wave*16+quad*4+r, col d = t*16+lm ----
    float liA[4], liB[4];
    #pragma unroll
    for (int r = 0; r < 4; r++) {
        liA[r] = 1.0f / __shfl(lA, quad * 4 + r, 64);
        liB[r] = 1.0f / __shfl(lB, quad * 4 + r, 64);
    }
    #pragma unroll
    for (int t = 0; t < 4; t++)
        #pragma unroll
        for (int r = 0; r < 4; r++) {
            int d  = t * 16 + lm;
            int qa = q0A + wave * 16 + quad * 4 + r;
            int qb = q0B + wave * 16 + quad * 4 + r;
            Yb[((size_t)b * T_ + qa) * C_ + h * D_ + d] =
                (short)f2b(OA[t][r] * liA[r]);
            Yb[((size_t)b * T_ + qb) * C_ + h * D_ + d] =
                (short)f2b(OB[t][r] * liB[r]);
        }
}

// ---------------------------------------------------------------------------
extern "C" void kernel_launch(void* const* d_in, const int* in_sizes, int n_in,
                              void* d_out, int out_size, void* d_ws, size_t ws_size,
                              hipStream_t stream)
{
    const float* x      = (const float*)d_in[0];
    const float* W_attn = (const float*)d_in[1];
    const float* b_attn = (const float*)d_in[2];
    const float* W_proj = (const float*)d_in[3];
    const float* b_proj = (const float*)d_in[4];
    float* out = (float*)d_out;

    char* ws = (char*)d_ws;
    const size_t MB = 1024 * 1024;
    short* Qh   = (short*)(ws);            // 8 MB  [ 0, 8)
    short* Ql   = (short*)(ws +  8 * MB);  // 8 MB  [ 8,16)
    short* Kh   = (short*)(ws + 16 * MB);  // 8 MB  [16,24)
    short* Kl   = (short*)(ws + 24 * MB);  // 8 MB  [24,32)
    short* xh   = (short*)(ws + 32 * MB);  // 8 MB  [32,40)  dead after qkv_v
    short* xl   = (short*)(ws + 40 * MB);  // 8 MB  [40,48)  dead after qkv_qk
    short* WaTh = (short*)(ws + 48 * MB);  // 6 MB  [48,54)
    short* WaTl = (short*)(ws + 54 * MB);  // 6 MB  [54,60)
    short* WpT  = (short*)(ws + 60 * MB);  // 2 MB  [60,62)
    short* VT   = (short*)(ws + 40 * MB);  // 8 MB  aliases xl (born at qkv_v)
    short* Yb   = (short*)(ws + 32 * MB);  // 8 MB  aliases xh (born at attn)

    cvt_all<<<dim3(3072), 256, 0, stream>>>(x, xh, xl, W_attn, WaTh, WaTl,
                                            W_proj, WpT);

    qkv_qk <<<dim3(16, 32), 256, 0, stream>>>(xh, xl, WaTh, WaTl, b_attn,
                                              Qh, Ql, Kh, Kl);
    qkv_v  <<<dim3(8, 64), 256, 0, stream>>>(xh, WaTh + (size_t)2048 * C_,
                                             b_attn + 2048, VT);
    attn_mfma<<<dim3(512), 256, 0, stream>>>(Qh, Ql, Kh, Kl, VT, Yb);
    proj_mfma<<<dim3(8, 64), 256, 0, stream>>>(Yb, WpT, b_proj, out);
}

// Round 11
// 238.674 us; speedup vs baseline: 1.0606x; 1.0180x over previous
//
#include <hip/hip_runtime.h>
#include <hip/hip_bf16.h>

// Problem: CausalSelfAttention  B=2, T=2048, C=1024, H=16, D=64
// Round 23: XCD swizzle ISOLATED on the proven R17/R22 structure.
// R22 (cvt merge) was neutral -> gaps negligible. R14 bundled XCD-swizzle
// with dbuf: FETCH 70->41MB (locality works!) but time regressed -- blamed
// "swizzle lockstep" without evidence; dbuf-alone later measured neutral
// (R18), swizzle-alone NEVER measured. Mechanism for a win: the 2-barrier
// loop's vmcnt(0) drain serializes on the slowest staging load each K-step;
// FETCH 70MB vs 32MB unique inputs = many HBM misses (~900cy) where L2/L3
// hits (~200cy) are possible. Swizzle converts them (proven by R14's FETCH).
// Change: bijective XCD remap (wg=(fid&7)*64+fid>>3, 64 contiguous tiles
// per XCD) in qkv_qk/qkv_v/proj ONLY. Everything else byte-identical to
// R22 (passed, 242.96; best 241.58).
// ws (62 MB): Qh 8|Ql 8|Kh 8|Kl 8|xh 8(->Yb)|xl 8(->VT)|WaTh 6|WaTl 6|WpT 2

#define B_  2
#define T_  2048
#define C_  1024
#define H_  16
#define D_  64
#define M_  (B_ * T_)      // 4096
#define N3_ (3 * C_)       // 3072

typedef __attribute__((ext_vector_type(8))) short s16x8;
typedef __attribute__((ext_vector_type(4))) short s16x4;
typedef __attribute__((ext_vector_type(4))) float f32x4;

typedef const __attribute__((address_space(1))) unsigned int gu32_t;
typedef __attribute__((address_space(3))) unsigned int lu32_t;

#define MFMA16(a, b, c) __builtin_amdgcn_mfma_f32_16x16x32_bf16(a, b, c, 0, 0, 0)

__device__ __forceinline__ void gload_lds16(const short* g, short* l) {
    __builtin_amdgcn_global_load_lds((gu32_t*)g, (lu32_t*)l, 16, 0, 0);
}

__device__ __forceinline__ float b2f(unsigned short u) {
    return __uint_as_float(((unsigned)u) << 16);
}
__device__ __forceinline__ unsigned short f2b(float f) {   // RNE bf16 round
    unsigned u = __float_as_uint(f);
    return (unsigned short)((u + 0x7FFFu + ((u >> 16) & 1u)) >> 16);
}
__device__ __forceinline__ float fexp2(float x) {
#if __has_builtin(__builtin_amdgcn_exp2f)
    return __builtin_amdgcn_exp2f(x);
#else
    return exp2f(x);
#endif
}

// ---------------------------------------------------------------------------
// cvt_all: one dispatch for all input conversions (grid 3072).
//   bid [0,2048):    x fp32 -> (xh, xl) bf16 hi/lo split
//   bid [2048,2816): W_attn [C,3C] -> (WaTh, WaTl) bf16 [3C,C] T-split
//   bid [2816,3072): W_proj [C,C]  -> WpT bf16 [C,C] transpose
// Branch is uniform per block; regions independent.
// ---------------------------------------------------------------------------
__global__ __launch_bounds__(256) void cvt_all(
    const float* __restrict__ x,  short* __restrict__ xh,   short* __restrict__ xl,
    const float* __restrict__ Wa, short* __restrict__ WaTh, short* __restrict__ WaTl,
    const float* __restrict__ Wp, short* __restrict__ WpT)
{
    __shared__ short th[64][80];
    __shared__ short tl[64][80];
    const int tid = threadIdx.x;
    const int bid = blockIdx.x;

    if (bid < 2048) {
        // ---- x hi/lo split (16 MB fp32 -> 2x 8 MB bf16) ----
        int i = (bid * 256 + tid) * 8;
        float4 a = *(const float4*)&x[i];
        float4 b = *(const float4*)&x[i + 4];
        float v[8] = {a.x, a.y, a.z, a.w, b.x, b.y, b.z, b.w};
        s16x8 h, l;
        #pragma unroll
        for (int j = 0; j < 8; j++) {
            unsigned short hb = f2b(v[j]);
            h[j] = (short)hb;
            l[j] = (short)f2b(v[j] - b2f(hb));
        }
        *(s16x8*)&xh[i] = h;
        *(s16x8*)&xl[i] = l;
        return;
    }

    if (bid < 2816) {
        // ---- W_attn transpose + hi/lo split ----
        int r  = bid - 2048;            // 0..767
        int bx = r % 48, by = r / 48;   // (N3_/64, C_/64)
        const int k0 = by * 64, n0 = bx * 64;
        const int R = C_, Cn = N3_;
        {
            int rl = tid >> 4, cl = (tid & 15) * 4;
            #pragma unroll
            for (int i = 0; i < 4; i++) {
                int kr = rl + i * 16;
                float4 v4 = *(const float4*)&Wa[(size_t)(k0 + kr) * Cn + n0 + cl];
                float v[4] = {v4.x, v4.y, v4.z, v4.w};
                #pragma unroll
                for (int j = 0; j < 4; j++) {
                    unsigned short hb = f2b(v[j]);
                    th[cl + j][kr] = (short)hb;
                    tl[cl + j][kr] = (short)f2b(v[j] - b2f(hb));
                }
            }
        }
        __syncthreads();
        {
            int ro = tid >> 2, co = (tid & 3) * 16;
            *(s16x8*)&WaTh[(size_t)(n0 + ro) * R + k0 + co]     = *(s16x8*)&th[ro][co];
            *(s16x8*)&WaTh[(size_t)(n0 + ro) * R + k0 + co + 8] = *(s16x8*)&th[ro][co + 8];
            *(s16x8*)&WaTl[(size_t)(n0 + ro) * R + k0 + co]     = *(s16x8*)&tl[ro][co];
            *(s16x8*)&WaTl[(size_t)(n0 + ro) * R + k0 + co + 8] = *(s16x8*)&tl[ro][co + 8];
        }
        return;
    }

    {
        // ---- W_proj transpose (single bf16) ----
        int r  = bid - 2816;            // 0..255
        int bx = r & 15, by = r >> 4;   // (C_/64, C_/64)
        const int k0 = by * 64, n0 = bx * 64;
        const int R = C_, Cn = C_;
        {
            int rl = tid >> 4, cl = (tid & 15) * 4;
            #pragma unroll
            for (int i = 0; i < 4; i++) {
                int kr = rl + i * 16;
                float4 v = *(const float4*)&Wp[(size_t)(k0 + kr) * Cn + n0 + cl];
                th[cl + 0][kr] = (short)f2b(v.x);
                th[cl + 1][kr] = (short)f2b(v.y);
                th[cl + 2][kr] = (short)f2b(v.z);
                th[cl + 3][kr] = (short)f2b(v.w);
            }
        }
        __syncthreads();
        {
            int ro = tid >> 2, co = (tid & 3) * 16;
            *(s16x8*)&WpT[(size_t)(n0 + ro) * R + k0 + co]     = *(s16x8*)&th[ro][co];
            *(s16x8*)&WpT[(size_t)(n0 + ro) * R + k0 + co + 8] = *(s16x8*)&th[ro][co + 8];
        }
    }
}

// ---------------------------------------------------------------------------
// qkv_qk: Q,K columns (N=2048), bf16x3, hi/lo scatter. Q pre-scaled by
// 8*log2(e). 128x128 tile, grid (16,32). LDS 32 KB. 0-conflict granule
// swizzle. NEW: bijective XCD block remap (64 contiguous tiles per XCD).
// ---------------------------------------------------------------------------
__global__ __launch_bounds__(256) void qkv_qk(
    const short* __restrict__ Ah, const short* __restrict__ Al,
    const short* __restrict__ BTh, const short* __restrict__ BTl,
    const float* __restrict__ bias,
    short* __restrict__ Qh, short* __restrict__ Ql,
    short* __restrict__ Kh, short* __restrict__ Kl)
{
    __shared__ short Ash[128 * 32], Asl[128 * 32];
    __shared__ short Bsh[128 * 32], Bsl[128 * 32];

    const int tid  = threadIdx.x;
    const int wave = tid >> 6, lane = tid & 63;
    const int wm = wave >> 1, wn = wave & 1;
    const int lm = lane & 15, lq = lane >> 4;
    // XCD-aware bijective remap: 512 blocks, 64 consecutive tiles per XCD
    const int fid = blockIdx.y * 16 + blockIdx.x;
    const int wg  = (fid & 7) * 64 + (fid >> 3);
    const int n0  = (wg & 15) * 128;
    const int m0  = (wg >> 4) * 128;
    const int gr  = (lane >> 2);
    // swizzled SOURCE granule: slot (row,g) holds global granule g^((row>>1)&3)
    const int gc  = (((lane & 3) ^ ((lane >> 3) & 3)) << 3);
    // swizzled READ col: logical granule lq of row-in-seg lm lives at lq^((lm>>1)&3)
    const int sg  = ((lq ^ ((lm >> 1) & 3)) << 3);

    f32x4 acc[4][4] = {};

    for (int k0 = 0; k0 < C_; k0 += 32) {
        __syncthreads();
        #pragma unroll
        for (int j = 0; j < 2; j++) {
            int s = wave * 2 + j;
            int row = s * 16 + gr;
            size_t ga = (size_t)(m0 + row) * C_ + k0 + gc;
            size_t gb = (size_t)(n0 + row) * C_ + k0 + gc;
            gload_lds16(&Ah[ga],  &Ash[s * 512]);
            gload_lds16(&Al[ga],  &Asl[s * 512]);
            gload_lds16(&BTh[gb], &Bsh[s * 512]);
            gload_lds16(&BTl[gb], &Bsl[s * 512]);
        }
        __syncthreads();

        s16x8 ah[4], al[4], bh[4], bl[4];
        #pragma unroll
        for (int mi = 0; mi < 4; mi++) {
            int r = wm * 64 + mi * 16 + lm;
            ah[mi] = *(const s16x8*)&Ash[r * 32 + sg];
            al[mi] = *(const s16x8*)&Asl[r * 32 + sg];
        }
        #pragma unroll
        for (int nj = 0; nj < 4; nj++) {
            int r = wn * 64 + nj * 16 + lm;
            bh[nj] = *(const s16x8*)&Bsh[r * 32 + sg];
            bl[nj] = *(const s16x8*)&Bsl[r * 32 + sg];
        }
        #pragma unroll
        for (int mi = 0; mi < 4; mi++)
            #pragma unroll
            for (int nj = 0; nj < 4; nj++) {
                acc[mi][nj] = MFMA16(ah[mi], bh[nj], acc[mi][nj]);
                acc[mi][nj] = MFMA16(ah[mi], bl[nj], acc[mi][nj]);
                acc[mi][nj] = MFMA16(al[mi], bh[nj], acc[mi][nj]);
            }
    }

    #pragma unroll
    for (int nj = 0; nj < 4; nj++) {
        int n = n0 + wn * 64 + nj * 16 + lm;
        float bv = bias[n];
        int isK = n >> 10;
        int c = n & (C_ - 1);
        int h = c >> 6, d = c & (D_ - 1);
        short* dh = isK ? Kh : Qh;
        short* dl = isK ? Kl : Ql;
        // Q carries sqrt(D)=8 and log2(e): softmax runs in exp2 domain
        float scale = isK ? 1.0f : 11.541560327111708f;   // 8*log2(e)
        #pragma unroll
        for (int mi = 0; mi < 4; mi++) {
            #pragma unroll
            for (int r = 0; r < 4; r++) {
                int m  = m0 + wm * 64 + mi * 16 + lq * 4 + r;
                int bb = m >> 11, t = m & (T_ - 1);
                float v = (acc[mi][nj][r] + bv) * scale;
                size_t idx = (((size_t)bb * H_ + h) * T_ + t) * D_ + d;
                unsigned short hb = f2b(v);
                dh[idx] = (short)hb;
                dl[idx] = (short)f2b(v - b2f(hb));
            }
        }
    }
}

// ---------------------------------------------------------------------------
// qkv_v: V columns (N=1024), single bf16, scatter TRANSPOSED -> VT [B,H,D,T].
// 64x128 tile, grid (8,64) = 512 blocks. Swizzled LDS + XCD remap.
// ---------------------------------------------------------------------------
__global__ __launch_bounds__(256, 4) void qkv_v(
    const short* __restrict__ Ah, const short* __restrict__ BTh,
    const float* __restrict__ bias, short* __restrict__ VT)
{
    __shared__ short Ash[64 * 32];    // 4 KB
    __shared__ short Bsh[128 * 32];   // 8 KB

    const int tid  = threadIdx.x;
    const int wave = tid >> 6, lane = tid & 63;
    const int wm = wave >> 1, wn = wave & 1;
    const int lm = lane & 15, lq = lane >> 4;
    // XCD remap: 512 blocks, 64 consecutive tiles per XCD
    const int fid = blockIdx.y * 8 + blockIdx.x;
    const int wg  = (fid & 7) * 64 + (fid >> 3);
    const int n0  = (wg & 7) * 128;
    const int m0  = (wg >> 3) * 64;
    const int gr  = (lane >> 2);
    const int gc  = (((lane & 3) ^ ((lane >> 3) & 3)) << 3);
    const int sg  = ((lq ^ ((lm >> 1) & 3)) << 3);

    f32x4 acc[2][4] = {};

    for (int k0 = 0; k0 < C_; k0 += 32) {
        __syncthreads();
        {
            int rowA = wave * 16 + gr;
            gload_lds16(&Ah[(size_t)(m0 + rowA) * C_ + k0 + gc], &Ash[wave * 512]);
            #pragma unroll
            for (int j = 0; j < 2; j++) {
                int s = wave * 2 + j;
                int rowB = s * 16 + gr;
                gload_lds16(&BTh[(size_t)(n0 + rowB) * C_ + k0 + gc], &Bsh[s * 512]);
            }
        }
        __syncthreads();

        s16x8 af[2], bfr[4];
        #pragma unroll
        for (int mi = 0; mi < 2; mi++)
            af[mi] = *(const s16x8*)&Ash[(wm * 32 + mi * 16 + lm) * 32 + sg];
        #pragma unroll
        for (int nj = 0; nj < 4; nj++)
            bfr[nj] = *(const s16x8*)&Bsh[(wn * 64 + nj * 16 + lm) * 32 + sg];
        #pragma unroll
        for (int mi = 0; mi < 2; mi++)
            #pragma unroll
            for (int nj = 0; nj < 4; nj++)
                acc[mi][nj] = MFMA16(af[mi], bfr[nj], acc[mi][nj]);
    }

    #pragma unroll
    for (int nj = 0; nj < 4; nj++) {
        int n = n0 + wn * 64 + nj * 16 + lm;    // [0, 1024) V channel
        float bv = bias[n];
        int h = n >> 6, d = n & (D_ - 1);
        #pragma unroll
        for (int mi = 0; mi < 2; mi++) {
            #pragma unroll
            for (int r = 0; r < 4; r++) {
                int m  = m0 + wm * 32 + mi * 16 + lq * 4 + r;
                int bb = m >> 11, t = m & (T_ - 1);
                VT[(((size_t)bb * H_ + h) * D_ + d) * T_ + t] =
                    (short)f2b(acc[mi][nj][r] + bv);
            }
        }
    }
}

// ---------------------------------------------------------------------------
// proj: out fp32 [M,C] = Yb(bf16) @ WpT(bf16) + bias. 64x128 tile, grid 512.
// Swizzled LDS + XCD remap.
// ---------------------------------------------------------------------------
__global__ __launch_bounds__(256, 4) void proj_mfma(
    const short* __restrict__ Ah, const short* __restrict__ BTh,
    const float* __restrict__ bias, float* __restrict__ out)
{
    __shared__ short Ash[64 * 32];
    __shared__ short Bsh[128 * 32];

    const int tid  = threadIdx.x;
    const int wave = tid >> 6, lane = tid & 63;
    const int wm = wave >> 1, wn = wave & 1;
    const int lm = lane & 15, lq = lane >> 4;
    const int fid = blockIdx.y * 8 + blockIdx.x;
    const int wg  = (fid & 7) * 64 + (fid >> 3);
    const int n0  = (wg & 7) * 128;
    const int m0  = (wg >> 3) * 64;
    const int gr  = (lane >> 2);
    const int gc  = (((lane & 3) ^ ((lane >> 3) & 3)) << 3);
    const int sg  = ((lq ^ ((lm >> 1) & 3)) << 3);

    f32x4 acc[2][4] = {};

    for (int k0 = 0; k0 < C_; k0 += 32) {
        __syncthreads();
        {
            int rowA = wave * 16 + gr;
            gload_lds16(&Ah[(size_t)(m0 + rowA) * C_ + k0 + gc], &Ash[wave * 512]);
            #pragma unroll
            for (int j = 0; j < 2; j++) {
                int s = wave * 2 + j;
                int rowB = s * 16 + gr;
                gload_lds16(&BTh[(size_t)(n0 + rowB) * C_ + k0 + gc], &Bsh[s * 512]);
            }
        }
        __syncthreads();

        s16x8 af[2], bfr[4];
        #pragma unroll
        for (int mi = 0; mi < 2; mi++)
            af[mi] = *(const s16x8*)&Ash[(wm * 32 + mi * 16 + lm) * 32 + sg];
        #pragma unroll
        for (int nj = 0; nj < 4; nj++)
            bfr[nj] = *(const s16x8*)&Bsh[(wn * 64 + nj * 16 + lm) * 32 + sg];
        #pragma unroll
        for (int mi = 0; mi < 2; mi++)
            #pragma unroll
            for (int nj = 0; nj < 4; nj++)
                acc[mi][nj] = MFMA16(af[mi], bfr[nj], acc[mi][nj]);
    }

    #pragma unroll
    for (int nj = 0; nj < 4; nj++) {
        int n = n0 + wn * 64 + nj * 16 + lm;
        float bv = bias[n];
        #pragma unroll
        for (int mi = 0; mi < 2; mi++) {
            #pragma unroll
            for (int r = 0; r < 4; r++) {
                int m = m0 + wm * 32 + mi * 16 + lq * 4 + r;
                out[(size_t)m * C_ + n] = acc[mi][nj][r] + bv;
            }
        }
    }
}

// ---------------------------------------------------------------------------
// online softmax (exp2 domain) with defer-max (THR=8). S in/out: S^T frag,
// per-thread 16 values for q-row lm. On exit S holds P = exp2(S - m).
// ---------------------------------------------------------------------------
__device__ __forceinline__ void online_sm(
    f32x4 S[4], float& mrow, float& lrow, f32x4 O[4], int quad)
{
    float v[16];
    #pragma unroll
    for (int t = 0; t < 4; t++)
        #pragma unroll
        for (int r = 0; r < 4; r++) v[t * 4 + r] = S[t][r];
    #pragma unroll
    for (int s = 8; s; s >>= 1)
        #pragma unroll
        for (int i = 0; i < s; i++) v[i] = fmaxf(v[i], v[i + s]);
    float rm = v[0];
    rm = fmaxf(rm, __shfl_xor(rm, 16, 64));
    rm = fmaxf(rm, __shfl_xor(rm, 32, 64));
    // defer-max: only rescale when some row grew by > 8 (=2^8 headroom)
    if (!__all(rm - mrow <= 8.f)) {
        float mnew  = fmaxf(mrow, rm);
        float alpha = fexp2(mrow - mnew);
        mrow = mnew;
        lrow *= alpha;
        float al[4];
        #pragma unroll
        for (int r = 0; r < 4; r++) al[r] = __shfl(alpha, quad * 4 + r, 64);
        #pragma unroll
        for (int t = 0; t < 4; t++)
            #pragma unroll
            for (int r = 0; r < 4; r++) O[t][r] *= al[r];
    }
    float sv[16];
    #pragma unroll
    for (int t = 0; t < 4; t++)
        #pragma unroll
        for (int r = 0; r < 4; r++) {
            float p = fexp2(S[t][r] - mrow);
            S[t][r] = p;
            sv[t * 4 + r] = p;
        }
    #pragma unroll
    for (int s = 8; s; s >>= 1)
        #pragma unroll
        for (int i = 0; i < s; i++) sv[i] += sv[i + s];
    float rs = sv[0];
    rs += __shfl_xor(rs, 16, 64);
    rs += __shfl_xor(rs, 32, 64);
    lrow += rs;
}

// ---------------------------------------------------------------------------
// MFMA flash attention, S^T layout, PAIRED q-tiles per block. Grid 512.
// Block handles qtA=j (j in 0..15) and qtB=31-j of one (b,h): exactly 33
// compute-units each. K/V staged once per kt, shared by both tiles; for
// kt<=j one LDS k-frag read feeds 6 MFMAs (dual chains = intra-wave ILP).
// Slot map pairs j with 15-j -> per-CU iteration count 49 (constant).
// LDS 40KB, XOR-swizzled [64][64] (conflict-free), 2 blocks/CU.
// Q pre-scaled by 8*log2e; softmax exp2-domain with defer-max. (R17-exact)
// ---------------------------------------------------------------------------
__global__ __launch_bounds__(256, 2) void attn_mfma(
    const short* __restrict__ Qh, const short* __restrict__ Ql,
    const short* __restrict__ Kh, const short* __restrict__ Kl,
    const short* __restrict__ VT, short* __restrict__ Yb)
{
    __shared__ short Ksh[64][64], Ksl[64][64];   // [key][d], XOR-swizzled
    __shared__ short Vt [64][64];                // [d][key], XOR-swizzled
    __shared__ short Ps [4][2][16][64];          // per-wave P slabs (B=0,A=1)

    const int tid  = threadIdx.x;
    const int wave = tid >> 6, lane = tid & 63;
    const int lm   = lane & 15, quad = lane >> 4;
    const int swz  = (lm & 7) << 3;              // read-side XOR (shorts)

    const int bid = blockIdx.x;                  // 512 blocks
    const int xcd = bid & 7;
    const int r_  = bid >> 3;                    // 0..63 per XCD
    const int bhl = r_ & 3;
    const int u   = r_ >> 2;                     // 0..15
    const int g_  = u >> 3, j_ = u & 7;
    const int j   = g_ ? (15 - j_) : j_;         // CU slot pairs j with 15-j
    const int bh  = xcd * 4 + bhl;
    const int b   = bh >> 4, h = bh & (H_ - 1);
    const int qtA = j, qtB = 31 - j;
    const int q0A = qtA * 64, q0B = qtB * 64;
    const size_t base  = (size_t)bh * T_ * D_;   // Q,K: [b,h,t,d]
    const size_t vbase = (size_t)bh * D_ * T_;   // VT:  [b,h,d,t]

    const int src = tid >> 3;                    // staging row 0..31 (+32)
    const int sch = (tid & 7) * 8;               // linear global col (shorts)
    const int wsw = sch ^ ((src & 7) << 3);      // swizzled LDS write col

    // ---- Q frags direct from global (L2-hit, once per block) ----
    s16x8 bqhA[2], bqlA[2], bqhB[2], bqlB[2];
    #pragma unroll
    for (int kc = 0; kc < 2; kc++) {
        size_t ga = base + (size_t)(q0A + wave * 16 + lm) * D_ + kc * 32 + quad * 8;
        size_t gb = base + (size_t)(q0B + wave * 16 + lm) * D_ + kc * 32 + quad * 8;
        bqhA[kc] = *(const s16x8*)&Qh[ga];
        bqlA[kc] = *(const s16x8*)&Ql[ga];
        bqhB[kc] = *(const s16x8*)&Qh[gb];
        bqlB[kc] = *(const s16x8*)&Ql[gb];
    }

    // ---- prefetch k-tile 0 into registers ----
    s16x8 pkh[2], pkl[2], pvt[2];
    #pragma unroll
    for (int i = 0; i < 2; i++) {
        int row = i * 32 + src;
        size_t gk = base + (size_t)row * D_ + sch;
        pkh[i] = *(const s16x8*)&Kh[gk];
        pkl[i] = *(const s16x8*)&Kl[gk];
        pvt[i] = *(const s16x8*)&VT[vbase + (size_t)row * T_ + sch];
    }

    float mA = -INFINITY, lA = 0.f;
    float mB = -INFINITY, lB = 0.f;
    f32x4 OA[4] = {}, OB[4] = {};

    for (int kt = 0; kt <= qtB; kt++) {
        __syncthreads();                          // prev tile's readers done
        #pragma unroll
        for (int i = 0; i < 2; i++) {             // VGPR -> LDS (swizzled)
            int row = i * 32 + src;
            *(s16x8*)&Ksh[row][wsw] = pkh[i];
            *(s16x8*)&Ksl[row][wsw] = pkl[i];
            *(s16x8*)&Vt [row][wsw] = pvt[i];
        }
        if (kt < qtB) {                           // issue next tile's loads
            #pragma unroll
            for (int i = 0; i < 2; i++) {
                int row = i * 32 + src;
                size_t gk = base + (size_t)((kt + 1) * 64 + row) * D_ + sch;
                pkh[i] = *(const s16x8*)&Kh[gk];
                pkl[i] = *(const s16x8*)&Kl[gk];
                pvt[i] = *(const s16x8*)&VT[vbase + (size_t)row * T_ + (kt + 1) * 64 + sch];
            }
        }
        __syncthreads();

        const bool doA = (kt <= qtA);
        const int  qg  = wave * 16 + lm;

        f32x4 SB[4] = {}, SA[4] = {};
        if (doA) {
            // dual: one k-frag read feeds 6 MFMAs (two independent chains)
            #pragma unroll
            for (int t = 0; t < 4; t++)
                #pragma unroll
                for (int kc = 0; kc < 2; kc++) {
                    s16x8 kh8 = *(const s16x8*)&Ksh[t * 16 + lm][(kc * 32 + quad * 8) ^ swz];
                    s16x8 kl8 = *(const s16x8*)&Ksl[t * 16 + lm][(kc * 32 + quad * 8) ^ swz];
                    SB[t] = MFMA16(kh8, bqhB[kc], SB[t]);
                    SB[t] = MFMA16(kl8, bqhB[kc], SB[t]);
                    SB[t] = MFMA16(kh8, bqlB[kc], SB[t]);
                    SA[t] = MFMA16(kh8, bqhA[kc], SA[t]);
                    SA[t] = MFMA16(kl8, bqhA[kc], SA[t]);
                    SA[t] = MFMA16(kh8, bqlA[kc], SA[t]);
                }
        } else {
            #pragma unroll
            for (int t = 0; t < 4; t++)
                #pragma unroll
                for (int kc = 0; kc < 2; kc++) {
                    s16x8 kh8 = *(const s16x8*)&Ksh[t * 16 + lm][(kc * 32 + quad * 8) ^ swz];
                    s16x8 kl8 = *(const s16x8*)&Ksl[t * 16 + lm][(kc * 32 + quad * 8) ^ swz];
                    SB[t] = MFMA16(kh8, bqhB[kc], SB[t]);
                    SB[t] = MFMA16(kl8, bqhB[kc], SB[t]);
                    SB[t] = MFMA16(kh8, bqlB[kc], SB[t]);
                }
        }

        // causal masks (scale pre-folded into Q)
        if (kt == qtB) {
            #pragma unroll
            for (int t = 0; t < 4; t++)
                #pragma unroll
                for (int r = 0; r < 4; r++)
                    if ((t * 16 + quad * 4 + r) > qg) SB[t][r] = -INFINITY;
        }
        if (kt == qtA) {
            #pragma unroll
            for (int t = 0; t < 4; t++)
                #pragma unroll
                for (int r = 0; r < 4; r++)
                    if ((t * 16 + quad * 4 + r) > qg) SA[t][r] = -INFINITY;
        }

        // ---- softmax (dual chains are independent) ----
        online_sm(SB, mB, lB, OB, quad);
        if (doA) online_sm(SA, mA, lA, OA, quad);

        // ---- P^T -> Ps (truncating bf16; P in [0, 256]) ----
        #pragma unroll
        for (int t = 0; t < 4; t++) {
            s16x4 p;
            #pragma unroll
            for (int r = 0; r < 4; r++)
                p[r] = (short)(__float_as_uint(SB[t][r]) >> 16);
            *(s16x4*)&Ps[wave][0][lm][(t * 16 + quad * 4) ^ swz] = p;
        }
        if (doA) {
            #pragma unroll
            for (int t = 0; t < 4; t++) {
                s16x4 p;
                #pragma unroll
                for (int r = 0; r < 4; r++)
                    p[r] = (short)(__float_as_uint(SA[t][r]) >> 16);
                *(s16x4*)&Ps[wave][1][lm][(t * 16 + quad * 4) ^ swz] = p;
            }
        }
        // wave-private slabs: no barrier (lgkmcnt ordering within wave)

        // ---- O += P V: shared Vt frag feeds both tiles ----
        s16x8 apB[2], apA[2];
        #pragma unroll
        for (int kc = 0; kc < 2; kc++)
            apB[kc] = *(const s16x8*)&Ps[wave][0][lm][(kc * 32 + quad * 8) ^ swz];
        if (doA) {
            #pragma unroll
            for (int kc = 0; kc < 2; kc++)
                apA[kc] = *(const s16x8*)&Ps[wave][1][lm][(kc * 32 + quad * 8) ^ swz];
            #pragma unroll
            for (int t = 0; t < 4; t++)
                #pragma unroll
                for (int kc = 0; kc < 2; kc++) {
                    s16x8 bv = *(const s16x8*)&Vt[t * 16 + lm][(kc * 32 + quad * 8) ^ swz];
                    OB[t] = MFMA16(apB[kc], bv, OB[t]);
                    OA[t] = MFMA16(apA[kc], bv, OA[t]);
                }
        } else {
            #pragma unroll
            for (int t = 0; t < 4; t++)
                #pragma unroll
                for (int kc = 0; kc < 2; kc++) {
                    s16x8 bv = *(const s16x8*)&Vt[t * 16 + lm][(kc * 32 + quad * 8) ^ swz];
                    OB[t] = MFMA16(apB[kc], bv, OB[t]);
                }
        }
    }

    // ---- epilogue: O row q = wave*16+quad*4+r, col d = t*16+lm ----
    float liA[4], liB[4];
    #pragma unroll
    for (int r = 0; r < 4; r++) {
        liA[r] = 1.0f / __shfl(lA, quad * 4 + r, 64);
        liB[r] = 1.0f / __shfl(lB, quad * 4 + r, 64);
    }
    #pragma unroll
    for (int t = 0; t < 4; t++)
        #pragma unroll
        for (int r = 0; r < 4; r++) {
            int d  = t * 16 + lm;
            int qa = q0A + wave * 16 + quad * 4 + r;
            int qb = q0B + wave * 16 + quad * 4 + r;
            Yb[((size_t)b * T_ + qa) * C_ + h * D_ + d] =
                (short)f2b(OA[t][r] * liA[r]);
            Yb[((size_t)b * T_ + qb) * C_ + h * D_ + d] =
                (short)f2b(OB[t][r] * liB[r]);
        }
}

// ---------------------------------------------------------------------------
extern "C" void kernel_launch(void* const* d_in, const int* in_sizes, int n_in,
                              void* d_out, int out_size, void* d_ws, size_t ws_size,
                              hipStream_t stream)
{
    const float* x      = (const float*)d_in[0];
    const float* W_attn = (const float*)d_in[1];
    const float* b_attn = (const float*)d_in[2];
    const float* W_proj = (const float*)d_in[3];
    const float* b_proj = (const float*)d_in[4];
    float* out = (float*)d_out;

    char* ws = (char*)d_ws;
    const size_t MB = 1024 * 1024;
    short* Qh   = (short*)(ws);            // 8 MB  [ 0, 8)
    short* Ql   = (short*)(ws +  8 * MB);  // 8 MB  [ 8,16)
    short* Kh   = (short*)(ws + 16 * MB);  // 8 MB  [16,24)
    short* Kl   = (short*)(ws + 24 * MB);  // 8 MB  [24,32)
    short* xh   = (short*)(ws + 32 * MB);  // 8 MB  [32,40)  dead after qkv_v
    short* xl   = (short*)(ws + 40 * MB);  // 8 MB  [40,48)  dead after qkv_qk
    short* WaTh = (short*)(ws + 48 * MB);  // 6 MB  [48,54)
    short* WaTl = (short*)(ws + 54 * MB);  // 6 MB  [54,60)
    short* WpT  = (short*)(ws + 60 * MB);  // 2 MB  [60,62)
    short* VT   = (short*)(ws + 40 * MB);  // 8 MB  aliases xl (born at qkv_v)
    short* Yb   = (short*)(ws + 32 * MB);  // 8 MB  aliases xh (born at attn)

    cvt_all<<<dim3(3072), 256, 0, stream>>>(x, xh, xl, W_attn, WaTh, WaTl,
                                            W_proj, WpT);

    qkv_qk <<<dim3(16, 32), 256, 0, stream>>>(xh, xl, WaTh, WaTl, b_attn,
                                              Qh, Ql, Kh, Kl);
    qkv_v  <<<dim3(8, 64), 256, 0, stream>>>(xh, WaTh + (size_t)2048 * C_,
                                             b_attn + 2048, VT);
    attn_mfma<<<dim3(512), 256, 0, stream>>>(Qh, Ql, Kh, Kl, VT, Yb);
    proj_mfma<<<dim3(8, 64), 256, 0, stream>>>(Yb, WpT, b_proj, out);
}